// Round 7
// baseline (272.169 us; speedup 1.0000x reference)
//
#include <hip/hip_runtime.h>

#define LRELU(x) ((x) > 0.0f ? (x) : 0.2f * (x))
#define SB __builtin_amdgcn_sched_barrier(0)

typedef short bf16x8 __attribute__((ext_vector_type(8)));
typedef short bf16x4 __attribute__((ext_vector_type(4)));
typedef float f32x4 __attribute__((ext_vector_type(4)));

__device__ __forceinline__ short f2bf(float f) {
  union { float f; unsigned u; } x{f};
  return (short)((x.u + 0x7FFF + ((x.u >> 16) & 1)) >> 16);
}

// ---------------------------------------------------------------------------
// fused prologue: weight repack (SOURCE-ordered coalesced reads, scattered
// stores) + head-bias out init + border zeroing + conv0 (blocks >= 10517).
__global__ __launch_bounds__(256) void k_repack_all(
    const float* __restrict__ w1, unsigned short* __restrict__ wr1,
    const float* __restrict__ w2, unsigned short* __restrict__ wr2,
    const float* __restrict__ bh, const int* __restrict__ sidx,
    float* __restrict__ out, unsigned short* __restrict__ x0t,
    unsigned short* __restrict__ ybf, const float* __restrict__ img,
    const float* __restrict__ w0, const float* __restrict__ b0) {
  __shared__ float Ish[4 * 34];
  if (blockIdx.x >= 10517) {
    // ---- conv0 segment: img (B,1,128,128) -> x0t padded 66x66 NHWC bf16
    const int t = threadIdx.x;
    const int q = blockIdx.x - 10517;
    const int b = q >> 8, py = q & 255;
    const int oh = py >> 2, owb = (py & 3) << 4;
    const int s = sidx[b];
    const float* ip = img + (size_t)b * 16384;
    if (t < 136) {
      int r = t / 34, c = t % 34;
      int ih = 2 * oh - 1 + r, iw = 2 * owb - 1 + c;
      Ish[t] = ((unsigned)ih < 128u && (unsigned)iw < 128u) ? ip[ih * 128 + iw] : 0.f;
    }
    const int co = t & 63, ps = t >> 6;
    float wreg[16];
    const float* wp = w0 + (s * 64 + co) * 16;
#pragma unroll
    for (int i = 0; i < 16; i++) wreg[i] = wp[i];
    float bb = b0[s * 64 + co];
    __syncthreads();
    unsigned short* op = x0t + ((size_t)b * 4356 + (oh + 1) * 66 + (owb + 1)) * 64 + co;
#pragma unroll
    for (int j = 0; j < 4; j++) {
      int pl = ps * 4 + j;
      float acc = bb;
#pragma unroll
      for (int kh = 0; kh < 4; kh++)
#pragma unroll
        for (int kw = 0; kw < 4; kw++)
          acc += wreg[kh * 4 + kw] * Ish[kh * 34 + pl * 2 + kw];
      acc = LRELU(acc);
      op[pl * 64] = (unsigned short)f2bf(acc);
    }
    return;
  }
  int idx = blockIdx.x * 256 + threadIdx.x;
  if (idx < 524288) {
    // w1: src-ordered. idx = ((s*128+co)*64+ci)*16+tap
    int tap = idx & 15;
    int rest = idx >> 4;
    int ci = rest & 63, sco = rest >> 6;
    wr1[(size_t)sco * 1024 + tap * 64 + ci] = (unsigned short)f2bf(w1[idx]);
    return;
  } else if (idx < 2621440) {
    // w2: src-ordered. i = ((s*256+co)*128+ci)*16+tap
    int i = idx - 524288;
    int tap = i & 15;
    int rest = i >> 4;
    int ci = rest & 127, sco = rest >> 7;
    wr2[(size_t)sco * 2048 + tap * 128 + ci] = (unsigned short)f2bf(w2[i]);
    return;
  } else if (idx < 2625040) {
    int i = idx - 2621440;
    if (i < 3600) out[i] = bh[sidx[i / 225]];
    return;
  } else if (idx < 2658320) {
    // zero x0t border: 16 b x 260 border pixels x 8 chunks (8 shorts each)
    int i = idx - 2625040;
    int b = i / 2080, r = i % 2080;
    int pix = r >> 3, sub = r & 7;
    int row, col;
    if (pix < 66) { row = 0; col = pix; }
    else if (pix < 132) { row = 65; col = pix - 66; }
    else { int qq = pix - 132; row = 1 + (qq >> 1); col = (qq & 1) * 65; }
    bf16x8 z = {0, 0, 0, 0, 0, 0, 0, 0};
    *(bf16x8*)(x0t + ((size_t)b * 4356 + row * 66 + col) * 64 + sub * 8) = z;
    return;
  } else {
    // zero ybf border: 16 b x 132 border pixels x 16 chunks (8 shorts each)
    int i = idx - 2658320;
    if (i >= 33792) return;
    int b = i / 2112, r = i % 2112;
    int pix = r >> 4, sub = r & 15;
    int row, col;
    if (pix < 34) { row = 0; col = pix; }
    else if (pix < 68) { row = 33; col = pix - 34; }
    else { int qq = pix - 68; row = 1 + (qq >> 1); col = (qq & 1) * 33; }
    bf16x8 z = {0, 0, 0, 0, 0, 0, 0, 0};
    *(bf16x8*)(ybf + ((size_t)b * 1156 + row * 34 + col) * 128 + sub * 8) = z;
    return;
  }
}

// ---------------------------------------------------------------------------
// conv1: high-occupancy (grid (B,64), 4 blocks/CU, 16 waves/CU via
// launch_bounds(256,4)) + SB-pinned depth-2 ping-pong (2-kc groups, 6 loads).
// Per wave: 32 co x 16 px, full K.
__global__ __launch_bounds__(256, 4) void k_conv1(
    const unsigned short* __restrict__ xt, const unsigned short* __restrict__ wr,
    const int* __restrict__ sidx, float* __restrict__ out) {
  constexpr int CI = 64, CO = 128;
  const int t = threadIdx.x;
  const int b = blockIdx.x;
  const int y = blockIdx.y;
  const int co0 = (y >> 5) * 64;
  const int n0 = (y & 31) * 32;
  const int s = sidx[b];
  const int lane = t & 63, wv = t >> 6;
  const int wm = (wv >> 1) * 32, wn = (wv & 1) * 16;
  const int quad = lane >> 4, l16 = lane & 15;

  const unsigned short* aptr0 = wr + (size_t)(s * CO + co0 + wm + l16) * (CI * 16) + quad * 8;
  const unsigned short* aptr1 = aptr0 + (size_t)16 * (CI * 16);
  const unsigned short* xb = xt + (size_t)b * 4356 * CI;
  const int p = n0 + wn + l16;
  const int pb = 2 * (p >> 5) * 66 + 2 * (p & 31);
  f32x4 acc[2];
  acc[0] = (f32x4){0.f, 0.f, 0.f, 0.f};
  acc[1] = (f32x4){0.f, 0.f, 0.f, 0.f};

  bf16x8 Aa0[2], Aa1[2], Ab[2];
  bf16x8 Ba0[2], Ba1[2], Bb[2];

#define LD1(A0, A1, BV, G)                                                  \
  _Pragma("unroll") for (int kk = 0; kk < 2; kk++) {                        \
    int kc = (G) * 2 + kk;                                                  \
    int tap = kc >> 1, cio = (kc & 1) * 32 + quad * 8;                      \
    int kh = tap >> 2, kw = tap & 3;                                        \
    A0[kk] = *(const bf16x8*)(aptr0 + kc * 32);                             \
    A1[kk] = *(const bf16x8*)(aptr1 + kc * 32);                             \
    BV[kk] = *(const bf16x8*)(xb + (size_t)(pb + kh * 66 + kw) * CI + cio); \
  }                                                                         \
  SB;

#define MM1(A0, A1, BV)                                                                  \
  _Pragma("unroll") for (int kk = 0; kk < 2; kk++) {                                     \
    acc[0] = __builtin_amdgcn_mfma_f32_16x16x32_bf16(A0[kk], BV[kk], acc[0], 0, 0, 0);   \
    acc[1] = __builtin_amdgcn_mfma_f32_16x16x32_bf16(A1[kk], BV[kk], acc[1], 0, 0, 0);   \
  }                                                                                      \
  SB;

  LD1(Aa0, Aa1, Ab, 0)
  LD1(Ba0, Ba1, Bb, 1)
  MM1(Aa0, Aa1, Ab) LD1(Aa0, Aa1, Ab, 2)
  MM1(Ba0, Ba1, Bb) LD1(Ba0, Ba1, Bb, 3)
  MM1(Aa0, Aa1, Ab) LD1(Aa0, Aa1, Ab, 4)
  MM1(Ba0, Ba1, Bb) LD1(Ba0, Ba1, Bb, 5)
  MM1(Aa0, Aa1, Ab) LD1(Aa0, Aa1, Ab, 6)
  MM1(Ba0, Ba1, Bb) LD1(Ba0, Ba1, Bb, 7)
  MM1(Aa0, Aa1, Ab) LD1(Aa0, Aa1, Ab, 8)
  MM1(Ba0, Ba1, Bb) LD1(Ba0, Ba1, Bb, 9)
  MM1(Aa0, Aa1, Ab) LD1(Aa0, Aa1, Ab, 10)
  MM1(Ba0, Ba1, Bb) LD1(Ba0, Ba1, Bb, 11)
  MM1(Aa0, Aa1, Ab) LD1(Aa0, Aa1, Ab, 12)
  MM1(Ba0, Ba1, Bb) LD1(Ba0, Ba1, Bb, 13)
  MM1(Aa0, Aa1, Ab) LD1(Aa0, Aa1, Ab, 14)
  MM1(Ba0, Ba1, Bb) LD1(Ba0, Ba1, Bb, 15)
  MM1(Aa0, Aa1, Ab)
  MM1(Ba0, Ba1, Bb)
#undef LD1
#undef MM1

#pragma unroll
  for (int i = 0; i < 2; i++) {
    int cobase = co0 + wm + i * 16 + quad * 4;
#pragma unroll
    for (int r = 0; r < 4; r++)
      out[((size_t)b * CO + cobase + r) * 1024 + p] = acc[i][r];
  }
}

// ---------------------------------------------------------------------------
// instance norm (+leaky): one wave per (b,c) row, float4 loads, no barriers.
template <int NPIX>
__global__ __launch_bounds__(256) void k_inormw(float* __restrict__ x) {
  constexpr int E = NPIX / 256;  // float4s per lane
  const int wv = threadIdx.x >> 6, lane = threadIdx.x & 63;
  const size_t row = (size_t)blockIdx.x * 4 + wv;
  float4* p = (float4*)(x + row * NPIX);
  float4 v[E];
#pragma unroll
  for (int i = 0; i < E; i++) v[i] = p[i * 64 + lane];
  float sum = 0.f, sq = 0.f;
#pragma unroll
  for (int i = 0; i < E; i++) {
    sum += v[i].x + v[i].y + v[i].z + v[i].w;
    sq += v[i].x * v[i].x + v[i].y * v[i].y + v[i].z * v[i].z + v[i].w * v[i].w;
  }
#pragma unroll
  for (int o = 32; o > 0; o >>= 1) {
    sum += __shfl_xor(sum, o, 64);
    sq += __shfl_xor(sq, o, 64);
  }
  float m = sum * (1.0f / NPIX);
  float var = sq * (1.0f / NPIX) - m * m;
  float inv = rsqrtf(var + 1e-5f);
#pragma unroll
  for (int i = 0; i < E; i++) {
    v[i].x = LRELU((v[i].x - m) * inv);
    v[i].y = LRELU((v[i].y - m) * inv);
    v[i].z = LRELU((v[i].z - m) * inv);
    v[i].w = LRELU((v[i].w - m) * inv);
    p[i * 64 + lane] = v[i];
  }
}

// ---------------------------------------------------------------------------
// fused q/k/v 1x1 projections. grid (B, 40): y<4 q, y<8 k, else v (chunked bf16)
__global__ __launch_bounds__(256) void k_proj_qkv(
    const float* __restrict__ xin, const float* __restrict__ wq,
    const float* __restrict__ bq, const float* __restrict__ wk,
    const float* __restrict__ bk, const float* __restrict__ wv,
    const float* __restrict__ bv, const int* __restrict__ sidx,
    float* __restrict__ q, float* __restrict__ kout, unsigned short* __restrict__ vpk) {
  __shared__ float xsh[32 * 256];
  __shared__ float wsh[16 * 32];
  const int t = threadIdx.x;
  const int b = blockIdx.x;
  const int y = blockIdx.y;
  const int s = sidx[b];
  const int cg = t >> 6, ng = t & 63;
  const float* w;
  const float* bias;
  int co0, nn0, CO;
  if (y < 8) {
    w = (y < 4) ? wq : wk;
    bias = (y < 4) ? bq : bk;
    co0 = 0;
    nn0 = (y & 3) * 256;
    CO = 16;
  } else {
    w = wv;
    bias = bv;
    co0 = ((y - 8) >> 2) * 16;
    nn0 = ((y - 8) & 3) * 256;
    CO = 128;
  }
  const float* xb = xin + (size_t)b * 128 * 1024;
  float4 acc4[4];
#pragma unroll
  for (int c = 0; c < 4; c++) {
    float bb = bias[s * CO + co0 + cg * 4 + c];
    acc4[c] = make_float4(bb, bb, bb, bb);
  }
  for (int cc = 0; cc < 4; cc++) {
#pragma unroll
    for (int k = 0; k < 8; k++) {
      int id = t + (k << 8);
      int ci = id >> 6, nf = id & 63;
      ((float4*)xsh)[id] = ((const float4*)(xb + (cc * 32 + ci) * 1024 + nn0))[nf];
    }
    if (t < 128)
      ((float4*)wsh)[t] =
          ((const float4*)(w + ((size_t)(s * CO + co0 + (t >> 3))) * 128 + cc * 32))[t & 7];
    __syncthreads();
#pragma unroll
    for (int ci4 = 0; ci4 < 8; ci4++) {
      float4 wvv[4], xv[4];
#pragma unroll
      for (int c = 0; c < 4; c++) wvv[c] = ((const float4*)wsh)[(cg * 4 + c) * 8 + ci4];
#pragma unroll
      for (int i = 0; i < 4; i++) xv[i] = ((const float4*)xsh)[(ci4 * 4 + i) * 64 + ng];
#pragma unroll
      for (int c = 0; c < 4; c++)
#pragma unroll
        for (int i = 0; i < 4; i++) {
          float wvc = i == 0 ? wvv[c].x : i == 1 ? wvv[c].y : i == 2 ? wvv[c].z : wvv[c].w;
          acc4[c].x += wvc * xv[i].x;
          acc4[c].y += wvc * xv[i].y;
          acc4[c].z += wvc * xv[i].z;
          acc4[c].w += wvc * xv[i].w;
        }
    }
    __syncthreads();
  }
  if (y < 8) {
    float* out = (y < 4) ? q : kout;
#pragma unroll
    for (int c = 0; c < 4; c++)
      ((float4*)(out + ((size_t)b * 16 + cg * 4 + c) * 1024 + nn0))[ng] = acc4[c];
  } else {
    int n = nn0 + ng * 4;
#pragma unroll
    for (int c = 0; c < 4; c++) {
      int co = co0 + cg * 4 + c;
      bf16x4 u;
      u[0] = f2bf(acc4[c].x);
      u[1] = f2bf(acc4[c].y);
      u[2] = f2bf(acc4[c].z);
      u[3] = f2bf(acc4[c].w);
      *(bf16x4*)(vpk + (((size_t)b * 32 + (n >> 5)) * 128 + co) * 32 + (n & 31)) = u;
    }
  }
}

// ---------------------------------------------------------------------------
// fused self-attention; SB-pinned ping-pong both phases; launch_bounds(256,4)
// so 4 blocks/CU become VGPR-feasible (LDS already allows 4).
__global__ __launch_bounds__(256, 4) void k_attn(
    const float* __restrict__ q, const float* __restrict__ k,
    const unsigned short* __restrict__ vpk, const float* __restrict__ x1,
    const float* __restrict__ gamma, const int* __restrict__ sidx,
    unsigned short* __restrict__ ybf) {
  __shared__ __align__(16) short Psh[16 * 1032];
  __shared__ float qsh[256];
  __shared__ float redm[64], reds[64];
  const int t = threadIdx.x;
  const int b = blockIdx.x >> 6;
  const int n0 = (blockIdx.x & 63) << 4;
  const int lane = t & 63, wv = t >> 6;
  const int quad = lane >> 4, l16 = lane & 15;
  const float* qb = q + (size_t)b * 16 * 1024;
  const float* kb = k + (size_t)b * 16 * 1024;
  const float* xb = x1 + (size_t)b * 128 * 1024;

  qsh[t] = qb[((t >> 4) << 10) + n0 + (t & 15)];
  __syncthreads();

  float acc[4][16];
#pragma unroll
  for (int j = 0; j < 4; j++)
#pragma unroll
    for (int nl = 0; nl < 16; nl++) acc[j][nl] = 0.0f;

  // --- QK^T: depth-2 ping-pong over 4-iteration K groups ---
  float4 KA[4], KB[4];
#define LDK(BUF, G)                                                       \
  _Pragma("unroll") for (int c4 = 0; c4 < 4; c4++)                        \
      BUF[c4] = *(const float4*)(kb + ((((G) * 4 + c4)) << 10) + 4 * t);  \
  SB;
#define MMK(BUF, G)                                                                         \
  _Pragma("unroll") for (int c4 = 0; c4 < 4; c4++) {                                        \
    const float* qr = qsh + ((G) * 4 + c4) * 16;                                            \
    _Pragma("unroll") for (int j = 0; j < 4; j++) {                                         \
      float kk = j == 0 ? BUF[c4].x : j == 1 ? BUF[c4].y : j == 2 ? BUF[c4].z : BUF[c4].w;  \
      _Pragma("unroll") for (int nl = 0; nl < 16; nl++) acc[j][nl] += kk * qr[nl];          \
    }                                                                                       \
  }                                                                                         \
  SB;

  LDK(KA, 0)
  LDK(KB, 1)
  MMK(KA, 0) LDK(KA, 2)
  MMK(KB, 1) LDK(KB, 3)
  MMK(KA, 2)
  MMK(KB, 3)
#undef LDK
#undef MMK

  float lmax[16];
#pragma unroll
  for (int nl = 0; nl < 16; nl++)
    lmax[nl] = fmaxf(fmaxf(acc[0][nl], acc[1][nl]), fmaxf(acc[2][nl], acc[3][nl]));
#pragma unroll
  for (int o = 32; o > 0; o >>= 1)
#pragma unroll
    for (int nl = 0; nl < 16; nl++) lmax[nl] = fmaxf(lmax[nl], __shfl_xor(lmax[nl], o, 64));
  if (lane == 0)
#pragma unroll
    for (int nl = 0; nl < 16; nl++) redm[wv * 16 + nl] = lmax[nl];
  __syncthreads();
#pragma unroll
  for (int nl = 0; nl < 16; nl++)
    lmax[nl] = fmaxf(fmaxf(redm[nl], redm[16 + nl]), fmaxf(redm[32 + nl], redm[48 + nl]));
  float lsum[16];
#pragma unroll
  for (int nl = 0; nl < 16; nl++) lsum[nl] = 0.0f;
#pragma unroll
  for (int j = 0; j < 4; j++)
#pragma unroll
    for (int nl = 0; nl < 16; nl++) {
      float e = __expf(acc[j][nl] - lmax[nl]);
      acc[j][nl] = e;
      lsum[nl] += e;
    }
#pragma unroll
  for (int o = 32; o > 0; o >>= 1)
#pragma unroll
    for (int nl = 0; nl < 16; nl++) lsum[nl] += __shfl_xor(lsum[nl], o, 64);
  if (lane == 0)
#pragma unroll
    for (int nl = 0; nl < 16; nl++) reds[wv * 16 + nl] = lsum[nl];
#pragma unroll
  for (int nl = 0; nl < 16; nl++) {
    bf16x4 pv;
    pv[0] = f2bf(acc[0][nl]);
    pv[1] = f2bf(acc[1][nl]);
    pv[2] = f2bf(acc[2][nl]);
    pv[3] = f2bf(acc[3][nl]);
    *(bf16x4*)&Psh[nl * 1032 + 4 * t] = pv;
  }
  __syncthreads();

  // --- PV: depth-2 ping-pong over 2-mt groups (fits 128-VGPR budget) ---
  const unsigned short* vp =
      vpk + ((size_t)b * 32 * 128 + (size_t)(wv * 32 + l16)) * 32 + quad * 8;
  const short* prow = Psh + l16 * 1032 + quad * 8;
  f32x4 dacc[2];
  dacc[0] = (f32x4){0.f, 0.f, 0.f, 0.f};
  dacc[1] = (f32x4){0.f, 0.f, 0.f, 0.f};

  bf16x8 VA0[2], VA1[2], PAr[2];
  bf16x8 VB0[2], VB1[2], PBr[2];
#define LDV(V0, V1, PR, G)                                \
  _Pragma("unroll") for (int m2 = 0; m2 < 2; m2++) {      \
    int mt = (G) * 2 + m2;                                \
    V0[m2] = *(const bf16x8*)(vp + mt * 4096);            \
    V1[m2] = *(const bf16x8*)(vp + 512 + mt * 4096);      \
    PR[m2] = *(const bf16x8*)(prow + mt * 32);            \
  }                                                       \
  SB;
#define MMV(V0, V1, PR)                                                                      \
  _Pragma("unroll") for (int m2 = 0; m2 < 2; m2++) {                                         \
    dacc[0] = __builtin_amdgcn_mfma_f32_16x16x32_bf16(V0[m2], PR[m2], dacc[0], 0, 0, 0);     \
    dacc[1] = __builtin_amdgcn_mfma_f32_16x16x32_bf16(V1[m2], PR[m2], dacc[1], 0, 0, 0);     \
  }                                                                                          \
  SB;

  LDV(VA0, VA1, PAr, 0)
  LDV(VB0, VB1, PBr, 1)
  MMV(VA0, VA1, PAr) LDV(VA0, VA1, PAr, 2)
  MMV(VB0, VB1, PBr) LDV(VB0, VB1, PBr, 3)
  MMV(VA0, VA1, PAr) LDV(VA0, VA1, PAr, 4)
  MMV(VB0, VB1, PBr) LDV(VB0, VB1, PBr, 5)
  MMV(VA0, VA1, PAr) LDV(VA0, VA1, PAr, 6)
  MMV(VB0, VB1, PBr) LDV(VB0, VB1, PBr, 7)
  MMV(VA0, VA1, PAr) LDV(VA0, VA1, PAr, 8)
  MMV(VB0, VB1, PBr) LDV(VB0, VB1, PBr, 9)
  MMV(VA0, VA1, PAr) LDV(VA0, VA1, PAr, 10)
  MMV(VB0, VB1, PBr) LDV(VB0, VB1, PBr, 11)
  MMV(VA0, VA1, PAr) LDV(VA0, VA1, PAr, 12)
  MMV(VB0, VB1, PBr) LDV(VB0, VB1, PBr, 13)
  MMV(VA0, VA1, PAr) LDV(VA0, VA1, PAr, 14)
  MMV(VB0, VB1, PBr) LDV(VB0, VB1, PBr, 15)
  MMV(VA0, VA1, PAr)
  MMV(VB0, VB1, PBr)
#undef LDV
#undef MMV
  __syncthreads();

  float* Osh = (float*)Psh;
  short* Osh2 = Psh + 4352;
#pragma unroll
  for (int i = 0; i < 2; i++) {
    int cob = wv * 32 + i * 16 + quad * 4;
#pragma unroll
    for (int r = 0; r < 4; r++) Osh[(cob + r) * 17 + l16] = dacc[i][r];
  }
  __syncthreads();
  float g = gamma[sidx[b]];
  {
    int co = t >> 1, j0 = (t & 1) * 8;
    const float* xr = xb + (co << 10) + n0 + j0;
    float4 xv0 = *(const float4*)xr;
    float4 xv1 = *(const float4*)(xr + 4);
    float xs[8] = {xv0.x, xv0.y, xv0.z, xv0.w, xv1.x, xv1.y, xv1.z, xv1.w};
#pragma unroll
    for (int j = 0; j < 8; j++) {
      int nl = j0 + j;
      float rs = 1.0f / (reds[nl] + reds[16 + nl] + reds[32 + nl] + reds[48 + nl]);
      Osh2[nl * 136 + co] = f2bf(g * Osh[co * 17 + nl] * rs + xs[j]);
    }
  }
  __syncthreads();
  {
    int nl = t >> 4, cg = t & 15;
    bf16x8 u = *(const bf16x8*)&Osh2[nl * 136 + cg * 8];
    int p = n0 + nl;
    int ih = p >> 5, iw = p & 31;
    *(bf16x8*)(ybf + ((size_t)b * 1156 + (ih + 1) * 34 + (iw + 1)) * 128 + cg * 8) = u;
  }
}

// ---------------------------------------------------------------------------
// conv2 (norm de-fused): high-occupancy grid (B,64), launch_bounds(256,4),
// SB-pinned depth-2 ping-pong (4-kc groups, 8 loads). Per wave: 16co x 16px.
__global__ __launch_bounds__(256, 4) void k_conv2(
    const unsigned short* __restrict__ ybf, const unsigned short* __restrict__ wr,
    const int* __restrict__ sidx, float* __restrict__ x2) {
  constexpr int CI = 128, CO = 256;
  const int t = threadIdx.x;
  const int b = blockIdx.x;
  const int y = blockIdx.y;
  const int co0 = (y >> 2) * 16;
  const int nq = y & 3;
  const int s = sidx[b];
  const int lane = t & 63, wv = t >> 6;
  const int quad = lane >> 4, l16 = lane & 15;

  const unsigned short* aptr = wr + (size_t)(s * CO + co0 + l16) * (CI * 16) + quad * 8;
  const unsigned short* xb = ybf + (size_t)b * 1156 * CI;
  const int p = nq * 64 + wv * 16 + l16;
  const int pb = 2 * (p >> 4) * 34 + 2 * (p & 15);
  f32x4 acc = (f32x4){0.f, 0.f, 0.f, 0.f};

  bf16x8 Aaf[4], Abv[4];
  bf16x8 Baf[4], Bbv[4];

#define LD2(AF, BV, G)                                                       \
  _Pragma("unroll") for (int kk = 0; kk < 4; kk++) {                         \
    int kc = (G) * 4 + kk;                                                   \
    int tap = kc >> 2, cio = (kc & 3) * 32 + quad * 8;                       \
    int kh = tap >> 2, kw = tap & 3;                                         \
    AF[kk] = *(const bf16x8*)(aptr + kc * 32);                               \
    BV[kk] = *(const bf16x8*)(xb + (size_t)(pb + kh * 34 + kw) * CI + cio);  \
  }                                                                          \
  SB;

#define MM2(AF, BV)                                                                \
  _Pragma("unroll") for (int kk = 0; kk < 4; kk++)                                 \
    acc = __builtin_amdgcn_mfma_f32_16x16x32_bf16(AF[kk], BV[kk], acc, 0, 0, 0);   \
  SB;

  LD2(Aaf, Abv, 0)
  LD2(Baf, Bbv, 1)
  MM2(Aaf, Abv) LD2(Aaf, Abv, 2)
  MM2(Baf, Bbv) LD2(Baf, Bbv, 3)
  MM2(Aaf, Abv) LD2(Aaf, Abv, 4)
  MM2(Baf, Bbv) LD2(Baf, Bbv, 5)
  MM2(Aaf, Abv) LD2(Aaf, Abv, 6)
  MM2(Baf, Bbv) LD2(Baf, Bbv, 7)
  MM2(Aaf, Abv) LD2(Aaf, Abv, 8)
  MM2(Baf, Bbv) LD2(Baf, Bbv, 9)
  MM2(Aaf, Abv) LD2(Aaf, Abv, 10)
  MM2(Baf, Bbv) LD2(Baf, Bbv, 11)
  MM2(Aaf, Abv) LD2(Aaf, Abv, 12)
  MM2(Baf, Bbv) LD2(Baf, Bbv, 13)
  MM2(Aaf, Abv) LD2(Aaf, Abv, 14)
  MM2(Baf, Bbv) LD2(Baf, Bbv, 15)
  MM2(Aaf, Abv)
  MM2(Baf, Bbv)
#undef LD2
#undef MM2

#pragma unroll
  for (int r = 0; r < 4; r++)
    x2[((size_t)b * CO + co0 + quad * 4 + r) * 256 + p] = acc[r];
}

// ---------------------------------------------------------------------------
// head: partial conv via LDS + atomicAdd (out pre-initialized with bias in
// k_repack_all's tail segment)
__global__ __launch_bounds__(256) void k_head_part(
    const float* __restrict__ x2, const float* __restrict__ wh,
    const int* __restrict__ sidx, float* __restrict__ out) {
  __shared__ float Xs[32 * 256];
  __shared__ float Wsh[512];
  const int t = threadIdx.x;
  const int b = blockIdx.x, cc = blockIdx.y;
  const int s = sidx[b];
  const float* xp = x2 + ((size_t)b * 256 + cc * 32) * 256;
#pragma unroll
  for (int i = 0; i < 32; i++) Xs[i * 256 + t] = xp[i * 256 + t];
#pragma unroll
  for (int i = 0; i < 2; i++) {
    int idx = i * 256 + t;
    Wsh[idx] = wh[s * 4096 + cc * 512 + idx];
  }
  __syncthreads();
  if (t < 225) {
    int oh = t / 15, ow = t % 15;
    float acc = 0.0f;
    for (int ci = 0; ci < 32; ci++) {
      const float* xr = Xs + ci * 256;
      const float* wr = Wsh + ci * 16;
#pragma unroll
      for (int kh = 0; kh < 4; kh++) {
        int ih = oh - 1 + kh;
        if ((unsigned)ih >= 16u) continue;
#pragma unroll
        for (int kw = 0; kw < 4; kw++) {
          int iw = ow - 1 + kw;
          if ((unsigned)iw >= 16u) continue;
          acc += wr[kh * 4 + kw] * xr[(ih << 4) + iw];
        }
      }
    }
    atomicAdd(out + b * 225 + t, acc);
  }
}

// ---------------------------------------------------------------------------
extern "C" void kernel_launch(void* const* d_in, const int* in_sizes, int n_in,
                              void* d_out, int out_size, void* d_ws, size_t ws_size,
                              hipStream_t stream) {
  const float* img = (const float*)d_in[0];
  const int* sidx = (const int*)d_in[1];
  const float* w0 = (const float*)d_in[2];
  const float* b0 = (const float*)d_in[3];
  const float* w1 = (const float*)d_in[4];
  const float* w2 = (const float*)d_in[6];
  const float* wq = (const float*)d_in[8];
  const float* bq = (const float*)d_in[9];
  const float* wk = (const float*)d_in[10];
  const float* bk = (const float*)d_in[11];
  const float* wv = (const float*)d_in[12];
  const float* bv = (const float*)d_in[13];
  const float* gamma = (const float*)d_in[14];
  const float* wh = (const float*)d_in[15];
  const float* bh = (const float*)d_in[16];
  float* out = (float*)d_out;

  float* ws = (float*)d_ws;
  unsigned short* x0t = (unsigned short*)(ws);            // padded 66x66: 16*4356*64 shorts
  float* x1 = ws + 2359296;                               // [2.25M,4.25M)
  float* q = ws + 4456448;                                // [4.25M,4.5M)
  float* k = ws + 4718592;                                // [4.5M,4.75M)
  unsigned short* vpk = (unsigned short*)(ws + 4980736);  // [4.75M,5.75M)
  unsigned short* ybf = (unsigned short*)(ws + 6029312);  // padded 34x34: 16*1156*128 shorts
  float* x2 = ws + 7340032;                               // [7M,8M)
  unsigned short* wr1 = (unsigned short*)(ws + 8912896);  // [8.5M,8.75M)
  unsigned short* wr2 = (unsigned short*)(ws + 9175040);  // [8.75M,9.75M)

  const int B = 16;

  // prologue: repack + bias-out + borders (blocks 0..10516) + conv0 (4096 blocks)
  k_repack_all<<<14613, 256, 0, stream>>>(w1, wr1, w2, wr2, bh, sidx, out, x0t, ybf,
                                          img, w0, b0);
  k_conv1<<<dim3(B, 64), 256, 0, stream>>>(x0t, wr1, sidx, x1);
  k_inormw<1024><<<512, 256, 0, stream>>>(x1);
  k_proj_qkv<<<dim3(B, 40), 256, 0, stream>>>(x1, wq, bq, wk, bk, wv, bv, sidx, q, k, vpk);
  k_attn<<<B * 64, 256, 0, stream>>>(q, k, vpk, x1, gamma, sidx, ybf);
  k_conv2<<<dim3(B, 64), 256, 0, stream>>>(ybf, wr2, sidx, x2);
  k_inormw<256><<<1024, 256, 0, stream>>>(x2);
  k_head_part<<<dim3(B, 8), 256, 0, stream>>>(x2, wh, sidx, out);
}

// Round 8
// 224.510 us; speedup vs baseline: 1.2123x; 1.2123x over previous
//
#include <hip/hip_runtime.h>

#define LRELU(x) ((x) > 0.0f ? (x) : 0.2f * (x))
#define SB __builtin_amdgcn_sched_barrier(0)

typedef short bf16x8 __attribute__((ext_vector_type(8)));
typedef short bf16x4 __attribute__((ext_vector_type(4)));
typedef float f32x4 __attribute__((ext_vector_type(4)));

__device__ __forceinline__ short f2bf(float f) {
  union { float f; unsigned u; } x{f};
  return (short)((x.u + 0x7FFF + ((x.u >> 16) & 1)) >> 16);
}

// ---------------------------------------------------------------------------
// fused prologue: weight repack (coalesced reads) + head-bias out init +
// border zeroing + conv0 (blocks >= 10517).
__global__ __launch_bounds__(256) void k_repack_all(
    const float* __restrict__ w1, unsigned short* __restrict__ wr1,
    const float* __restrict__ w2, unsigned short* __restrict__ wr2,
    const float* __restrict__ bh, const int* __restrict__ sidx,
    float* __restrict__ out, unsigned short* __restrict__ x0t,
    unsigned short* __restrict__ ybf, const float* __restrict__ img,
    const float* __restrict__ w0, const float* __restrict__ b0) {
  __shared__ float Ish[4 * 34];
  if (blockIdx.x >= 10517) {
    // ---- conv0 segment: img (B,1,128,128) -> x0t padded 66x66 NHWC bf16
    const int t = threadIdx.x;
    const int q = blockIdx.x - 10517;
    const int b = q >> 8, py = q & 255;
    const int oh = py >> 2, owb = (py & 3) << 4;
    const int s = sidx[b];
    const float* ip = img + (size_t)b * 16384;
    if (t < 136) {
      int r = t / 34, c = t % 34;
      int ih = 2 * oh - 1 + r, iw = 2 * owb - 1 + c;
      Ish[t] = ((unsigned)ih < 128u && (unsigned)iw < 128u) ? ip[ih * 128 + iw] : 0.f;
    }
    const int co = t & 63, ps = t >> 6;
    float wreg[16];
    const float* wp = w0 + (s * 64 + co) * 16;
#pragma unroll
    for (int i = 0; i < 16; i++) wreg[i] = wp[i];
    float bb = b0[s * 64 + co];
    __syncthreads();
    unsigned short* op = x0t + ((size_t)b * 4356 + (oh + 1) * 66 + (owb + 1)) * 64 + co;
#pragma unroll
    for (int j = 0; j < 4; j++) {
      int pl = ps * 4 + j;
      float acc = bb;
#pragma unroll
      for (int kh = 0; kh < 4; kh++)
#pragma unroll
        for (int kw = 0; kw < 4; kw++)
          acc += wreg[kh * 4 + kw] * Ish[kh * 34 + pl * 2 + kw];
      acc = LRELU(acc);
      op[pl * 64] = (unsigned short)f2bf(acc);
    }
    return;
  }
  int idx = blockIdx.x * 256 + threadIdx.x;
  if (idx < 524288) {
    // w1: src-ordered. idx = ((s*128+co)*64+ci)*16+tap
    int tap = idx & 15;
    int rest = idx >> 4;
    int ci = rest & 63, sco = rest >> 6;
    wr1[(size_t)sco * 1024 + tap * 64 + ci] = (unsigned short)f2bf(w1[idx]);
    return;
  } else if (idx < 2621440) {
    // w2: src-ordered. i = ((s*256+co)*128+ci)*16+tap
    int i = idx - 524288;
    int tap = i & 15;
    int rest = i >> 4;
    int ci = rest & 127, sco = rest >> 7;
    wr2[(size_t)sco * 2048 + tap * 128 + ci] = (unsigned short)f2bf(w2[i]);
    return;
  } else if (idx < 2625040) {
    int i = idx - 2621440;
    if (i < 3600) out[i] = bh[sidx[i / 225]];
    return;
  } else if (idx < 2658320) {
    // zero x0t border
    int i = idx - 2625040;
    int b = i / 2080, r = i % 2080;
    int pix = r >> 3, sub = r & 7;
    int row, col;
    if (pix < 66) { row = 0; col = pix; }
    else if (pix < 132) { row = 65; col = pix - 66; }
    else { int qq = pix - 132; row = 1 + (qq >> 1); col = (qq & 1) * 65; }
    bf16x8 z = {0, 0, 0, 0, 0, 0, 0, 0};
    *(bf16x8*)(x0t + ((size_t)b * 4356 + row * 66 + col) * 64 + sub * 8) = z;
    return;
  } else {
    // zero ybf border
    int i = idx - 2658320;
    if (i >= 33792) return;
    int b = i / 2112, r = i % 2112;
    int pix = r >> 4, sub = r & 15;
    int row, col;
    if (pix < 34) { row = 0; col = pix; }
    else if (pix < 68) { row = 33; col = pix - 34; }
    else { int qq = pix - 68; row = 1 + (qq >> 1); col = (qq & 1) * 33; }
    bf16x8 z = {0, 0, 0, 0, 0, 0, 0, 0};
    *(bf16x8*)(ybf + ((size_t)b * 1156 + row * 34 + col) * 128 + sub * 8) = z;
    return;
  }
}

// ---------------------------------------------------------------------------
// conv1: round-5 proven version. SB-pinned depth-2 ping-pong, (256,2).
__global__ __launch_bounds__(256, 2) void k_conv1(
    const unsigned short* __restrict__ xt, const unsigned short* __restrict__ wr,
    const int* __restrict__ sidx, float* __restrict__ out) {
  constexpr int CI = 64, CO = 128;
  constexpr int NPB = 1024, NT = 16;
  const int t = threadIdx.x;
  const int b = blockIdx.x;
  const int co0 = (blockIdx.y / NT) * 64;
  const int n0 = (blockIdx.y % NT) * 64;
  const int s = sidx[b];
  const int lane = t & 63, wv = t >> 6;
  const int wm = (wv >> 1) * 32, wn = (wv & 1) * 32;
  const int quad = lane >> 4, l16 = lane & 15;

  const unsigned short* aptr0 = wr + (size_t)(s * CO + co0 + wm + l16) * (CI * 16) + quad * 8;
  const unsigned short* aptr1 = aptr0 + (size_t)16 * (CI * 16);
  const unsigned short* xb = xt + (size_t)b * 4356 * CI;
  int pb0, pb1;
  {
    int p = n0 + wn + l16;
    pb0 = 2 * (p >> 5) * 66 + 2 * (p & 31);
    p += 16;
    pb1 = 2 * (p >> 5) * 66 + 2 * (p & 31);
  }
  f32x4 acc[2][2];
#pragma unroll
  for (int i = 0; i < 2; i++)
#pragma unroll
    for (int j = 0; j < 2; j++) acc[i][j] = (f32x4){0.f, 0.f, 0.f, 0.f};

  bf16x8 Aaf0[4], Aaf1[4], Abv0[4], Abv1[4];
  bf16x8 Baf0[4], Baf1[4], Bbv0[4], Bbv1[4];

#define LD1(AF0, AF1, BV0, BV1, G)                                            \
  _Pragma("unroll") for (int kk = 0; kk < 4; kk++) {                          \
    int kc = (G) * 4 + kk;                                                    \
    int tap = kc >> 1, cio = (kc & 1) * 32 + quad * 8;                        \
    int kh = tap >> 2, kw = tap & 3;                                          \
    AF0[kk] = *(const bf16x8*)(aptr0 + kc * 32);                              \
    AF1[kk] = *(const bf16x8*)(aptr1 + kc * 32);                              \
    BV0[kk] = *(const bf16x8*)(xb + (size_t)(pb0 + kh * 66 + kw) * CI + cio); \
    BV1[kk] = *(const bf16x8*)(xb + (size_t)(pb1 + kh * 66 + kw) * CI + cio); \
  }                                                                           \
  SB;

#define MM1(AF0, AF1, BV0, BV1)                                                                  \
  _Pragma("unroll") for (int kk = 0; kk < 4; kk++) {                                             \
    acc[0][0] = __builtin_amdgcn_mfma_f32_16x16x32_bf16(AF0[kk], BV0[kk], acc[0][0], 0, 0, 0);   \
    acc[1][0] = __builtin_amdgcn_mfma_f32_16x16x32_bf16(AF1[kk], BV0[kk], acc[1][0], 0, 0, 0);   \
    acc[0][1] = __builtin_amdgcn_mfma_f32_16x16x32_bf16(AF0[kk], BV1[kk], acc[0][1], 0, 0, 0);   \
    acc[1][1] = __builtin_amdgcn_mfma_f32_16x16x32_bf16(AF1[kk], BV1[kk], acc[1][1], 0, 0, 0);   \
  }                                                                                              \
  SB;

  LD1(Aaf0, Aaf1, Abv0, Abv1, 0)
  LD1(Baf0, Baf1, Bbv0, Bbv1, 1)
  MM1(Aaf0, Aaf1, Abv0, Abv1) LD1(Aaf0, Aaf1, Abv0, Abv1, 2)
  MM1(Baf0, Baf1, Bbv0, Bbv1) LD1(Baf0, Baf1, Bbv0, Bbv1, 3)
  MM1(Aaf0, Aaf1, Abv0, Abv1) LD1(Aaf0, Aaf1, Abv0, Abv1, 4)
  MM1(Baf0, Baf1, Bbv0, Bbv1) LD1(Baf0, Baf1, Bbv0, Bbv1, 5)
  MM1(Aaf0, Aaf1, Abv0, Abv1) LD1(Aaf0, Aaf1, Abv0, Abv1, 6)
  MM1(Baf0, Baf1, Bbv0, Bbv1) LD1(Baf0, Baf1, Bbv0, Bbv1, 7)
  MM1(Aaf0, Aaf1, Abv0, Abv1)
  MM1(Baf0, Baf1, Bbv0, Bbv1)
#undef LD1
#undef MM1

#pragma unroll
  for (int i = 0; i < 2; i++) {
    int cobase = co0 + wm + i * 16 + quad * 4;
#pragma unroll
    for (int j = 0; j < 2; j++) {
      int n = n0 + wn + j * 16 + l16;
#pragma unroll
      for (int r = 0; r < 4; r++)
        out[((size_t)b * CO + cobase + r) * NPB + n] = acc[i][j][r];
    }
  }
}

// ---------------------------------------------------------------------------
// in-place instance norm (+leaky), NPIX per (b,c) — proven block version
template <int NPIX>
__global__ __launch_bounds__(256) void k_inorm(float* __restrict__ x) {
  constexpr int E = NPIX / 256;
  float* p = x + (size_t)blockIdx.x * NPIX;
  const int t = threadIdx.x;
  float v[E];
  float sum = 0.f, sq = 0.f;
#pragma unroll
  for (int i = 0; i < E; i++) {
    v[i] = p[i * 256 + t];
    sum += v[i];
    sq += v[i] * v[i];
  }
#pragma unroll
  for (int o = 32; o > 0; o >>= 1) {
    sum += __shfl_down(sum, o, 64);
    sq += __shfl_down(sq, o, 64);
  }
  __shared__ float red[8];
  int wid = t >> 6;
  if ((t & 63) == 0) {
    red[wid] = sum;
    red[4 + wid] = sq;
  }
  __syncthreads();
  float S = red[0] + red[1] + red[2] + red[3];
  float SQ = red[4] + red[5] + red[6] + red[7];
  float m = S * (1.0f / NPIX);
  float var = SQ * (1.0f / NPIX) - m * m;
  float inv = rsqrtf(var + 1e-5f);
#pragma unroll
  for (int i = 0; i < E; i++) p[i * 256 + t] = LRELU((v[i] - m) * inv);
}

// ---------------------------------------------------------------------------
// instance norm (+leaky): one wave per (b,c) row, float4 loads, no barriers.
template <int NPIX>
__global__ __launch_bounds__(256) void k_inormw(float* __restrict__ x) {
  constexpr int E = NPIX / 256;  // float4s per lane
  const int wv = threadIdx.x >> 6, lane = threadIdx.x & 63;
  const size_t row = (size_t)blockIdx.x * 4 + wv;
  float4* p = (float4*)(x + row * NPIX);
  float4 v[E];
#pragma unroll
  for (int i = 0; i < E; i++) v[i] = p[i * 64 + lane];
  float sum = 0.f, sq = 0.f;
#pragma unroll
  for (int i = 0; i < E; i++) {
    sum += v[i].x + v[i].y + v[i].z + v[i].w;
    sq += v[i].x * v[i].x + v[i].y * v[i].y + v[i].z * v[i].z + v[i].w * v[i].w;
  }
#pragma unroll
  for (int o = 32; o > 0; o >>= 1) {
    sum += __shfl_xor(sum, o, 64);
    sq += __shfl_xor(sq, o, 64);
  }
  float m = sum * (1.0f / NPIX);
  float var = sq * (1.0f / NPIX) - m * m;
  float inv = rsqrtf(var + 1e-5f);
#pragma unroll
  for (int i = 0; i < E; i++) {
    v[i].x = LRELU((v[i].x - m) * inv);
    v[i].y = LRELU((v[i].y - m) * inv);
    v[i].z = LRELU((v[i].z - m) * inv);
    v[i].w = LRELU((v[i].w - m) * inv);
    p[i * 64 + lane] = v[i];
  }
}

// ---------------------------------------------------------------------------
// fused q/k/v 1x1 projections. grid (B, 40): y<4 q, y<8 k, else v (chunked bf16)
__global__ __launch_bounds__(256) void k_proj_qkv(
    const float* __restrict__ xin, const float* __restrict__ wq,
    const float* __restrict__ bq, const float* __restrict__ wk,
    const float* __restrict__ bk, const float* __restrict__ wv,
    const float* __restrict__ bv, const int* __restrict__ sidx,
    float* __restrict__ q, float* __restrict__ kout, unsigned short* __restrict__ vpk) {
  __shared__ float xsh[32 * 256];
  __shared__ float wsh[16 * 32];
  const int t = threadIdx.x;
  const int b = blockIdx.x;
  const int y = blockIdx.y;
  const int s = sidx[b];
  const int cg = t >> 6, ng = t & 63;
  const float* w;
  const float* bias;
  int co0, nn0, CO;
  if (y < 8) {
    w = (y < 4) ? wq : wk;
    bias = (y < 4) ? bq : bk;
    co0 = 0;
    nn0 = (y & 3) * 256;
    CO = 16;
  } else {
    w = wv;
    bias = bv;
    co0 = ((y - 8) >> 2) * 16;
    nn0 = ((y - 8) & 3) * 256;
    CO = 128;
  }
  const float* xb = xin + (size_t)b * 128 * 1024;
  float4 acc4[4];
#pragma unroll
  for (int c = 0; c < 4; c++) {
    float bb = bias[s * CO + co0 + cg * 4 + c];
    acc4[c] = make_float4(bb, bb, bb, bb);
  }
  for (int cc = 0; cc < 4; cc++) {
#pragma unroll
    for (int k = 0; k < 8; k++) {
      int id = t + (k << 8);
      int ci = id >> 6, nf = id & 63;
      ((float4*)xsh)[id] = ((const float4*)(xb + (cc * 32 + ci) * 1024 + nn0))[nf];
    }
    if (t < 128)
      ((float4*)wsh)[t] =
          ((const float4*)(w + ((size_t)(s * CO + co0 + (t >> 3))) * 128 + cc * 32))[t & 7];
    __syncthreads();
#pragma unroll
    for (int ci4 = 0; ci4 < 8; ci4++) {
      float4 wvv[4], xv[4];
#pragma unroll
      for (int c = 0; c < 4; c++) wvv[c] = ((const float4*)wsh)[(cg * 4 + c) * 8 + ci4];
#pragma unroll
      for (int i = 0; i < 4; i++) xv[i] = ((const float4*)xsh)[(ci4 * 4 + i) * 64 + ng];
#pragma unroll
      for (int c = 0; c < 4; c++)
#pragma unroll
        for (int i = 0; i < 4; i++) {
          float wvc = i == 0 ? wvv[c].x : i == 1 ? wvv[c].y : i == 2 ? wvv[c].z : wvv[c].w;
          acc4[c].x += wvc * xv[i].x;
          acc4[c].y += wvc * xv[i].y;
          acc4[c].z += wvc * xv[i].z;
          acc4[c].w += wvc * xv[i].w;
        }
    }
    __syncthreads();
  }
  if (y < 8) {
    float* out = (y < 4) ? q : kout;
#pragma unroll
    for (int c = 0; c < 4; c++)
      ((float4*)(out + ((size_t)b * 16 + cg * 4 + c) * 1024 + nn0))[ng] = acc4[c];
  } else {
    int n = nn0 + ng * 4;
#pragma unroll
    for (int c = 0; c < 4; c++) {
      int co = co0 + cg * 4 + c;
      bf16x4 u;
      u[0] = f2bf(acc4[c].x);
      u[1] = f2bf(acc4[c].y);
      u[2] = f2bf(acc4[c].z);
      u[3] = f2bf(acc4[c].w);
      *(bf16x4*)(vpk + (((size_t)b * 32 + (n >> 5)) * 128 + co) * 32 + (n & 31)) = u;
    }
  }
}

// ---------------------------------------------------------------------------
// fused self-attention — round-5 proven version (SB ping-pong, (256,2))
__global__ __launch_bounds__(256, 2) void k_attn(
    const float* __restrict__ q, const float* __restrict__ k,
    const unsigned short* __restrict__ vpk, const float* __restrict__ x1,
    const float* __restrict__ gamma, const int* __restrict__ sidx,
    unsigned short* __restrict__ ybf) {
  __shared__ __align__(16) short Psh[16 * 1032];
  __shared__ float qsh[256];
  __shared__ float redm[64], reds[64];
  const int t = threadIdx.x;
  const int b = blockIdx.x >> 6;
  const int n0 = (blockIdx.x & 63) << 4;
  const int lane = t & 63, wv = t >> 6;
  const int quad = lane >> 4, l16 = lane & 15;
  const float* qb = q + (size_t)b * 16 * 1024;
  const float* kb = k + (size_t)b * 16 * 1024;
  const float* xb = x1 + (size_t)b * 128 * 1024;

  qsh[t] = qb[((t >> 4) << 10) + n0 + (t & 15)];
  __syncthreads();

  float acc[4][16];
#pragma unroll
  for (int j = 0; j < 4; j++)
#pragma unroll
    for (int nl = 0; nl < 16; nl++) acc[j][nl] = 0.0f;

  float4 KA[4], KB[4];
#define LDK(BUF, G)                                                       \
  _Pragma("unroll") for (int c4 = 0; c4 < 4; c4++)                        \
      BUF[c4] = *(const float4*)(kb + ((((G) * 4 + c4)) << 10) + 4 * t);  \
  SB;
#define MMK(BUF, G)                                                                         \
  _Pragma("unroll") for (int c4 = 0; c4 < 4; c4++) {                                        \
    const float* qr = qsh + ((G) * 4 + c4) * 16;                                            \
    _Pragma("unroll") for (int j = 0; j < 4; j++) {                                         \
      float kk = j == 0 ? BUF[c4].x : j == 1 ? BUF[c4].y : j == 2 ? BUF[c4].z : BUF[c4].w;  \
      _Pragma("unroll") for (int nl = 0; nl < 16; nl++) acc[j][nl] += kk * qr[nl];          \
    }                                                                                       \
  }                                                                                         \
  SB;

  LDK(KA, 0)
  LDK(KB, 1)
  MMK(KA, 0) LDK(KA, 2)
  MMK(KB, 1) LDK(KB, 3)
  MMK(KA, 2)
  MMK(KB, 3)
#undef LDK
#undef MMK

  float lmax[16];
#pragma unroll
  for (int nl = 0; nl < 16; nl++)
    lmax[nl] = fmaxf(fmaxf(acc[0][nl], acc[1][nl]), fmaxf(acc[2][nl], acc[3][nl]));
#pragma unroll
  for (int o = 32; o > 0; o >>= 1)
#pragma unroll
    for (int nl = 0; nl < 16; nl++) lmax[nl] = fmaxf(lmax[nl], __shfl_xor(lmax[nl], o, 64));
  if (lane == 0)
#pragma unroll
    for (int nl = 0; nl < 16; nl++) redm[wv * 16 + nl] = lmax[nl];
  __syncthreads();
#pragma unroll
  for (int nl = 0; nl < 16; nl++)
    lmax[nl] = fmaxf(fmaxf(redm[nl], redm[16 + nl]), fmaxf(redm[32 + nl], redm[48 + nl]));
  float lsum[16];
#pragma unroll
  for (int nl = 0; nl < 16; nl++) lsum[nl] = 0.0f;
#pragma unroll
  for (int j = 0; j < 4; j++)
#pragma unroll
    for (int nl = 0; nl < 16; nl++) {
      float e = __expf(acc[j][nl] - lmax[nl]);
      acc[j][nl] = e;
      lsum[nl] += e;
    }
#pragma unroll
  for (int o = 32; o > 0; o >>= 1)
#pragma unroll
    for (int nl = 0; nl < 16; nl++) lsum[nl] += __shfl_xor(lsum[nl], o, 64);
  if (lane == 0)
#pragma unroll
    for (int nl = 0; nl < 16; nl++) reds[wv * 16 + nl] = lsum[nl];
#pragma unroll
  for (int nl = 0; nl < 16; nl++) {
    bf16x4 pv;
    pv[0] = f2bf(acc[0][nl]);
    pv[1] = f2bf(acc[1][nl]);
    pv[2] = f2bf(acc[2][nl]);
    pv[3] = f2bf(acc[3][nl]);
    *(bf16x4*)&Psh[nl * 1032 + 4 * t] = pv;
  }
  __syncthreads();

  const unsigned short* vp =
      vpk + ((size_t)b * 32 * 128 + (size_t)(wv * 32 + l16)) * 32 + quad * 8;
  const short* prow = Psh + l16 * 1032 + quad * 8;
  f32x4 dacc[2];
  dacc[0] = (f32x4){0.f, 0.f, 0.f, 0.f};
  dacc[1] = (f32x4){0.f, 0.f, 0.f, 0.f};

  bf16x8 VA0[4], VA1[4], PAr[4];
  bf16x8 VB0[4], VB1[4], PBr[4];
#define LDV(V0, V1, PR, G)                                \
  _Pragma("unroll") for (int m4 = 0; m4 < 4; m4++) {      \
    int mt = (G) * 4 + m4;                                \
    V0[m4] = *(const bf16x8*)(vp + mt * 4096);            \
    V1[m4] = *(const bf16x8*)(vp + 512 + mt * 4096);      \
    PR[m4] = *(const bf16x8*)(prow + mt * 32);            \
  }                                                       \
  SB;
#define MMV(V0, V1, PR)                                                                      \
  _Pragma("unroll") for (int m4 = 0; m4 < 4; m4++) {                                         \
    dacc[0] = __builtin_amdgcn_mfma_f32_16x16x32_bf16(V0[m4], PR[m4], dacc[0], 0, 0, 0);     \
    dacc[1] = __builtin_amdgcn_mfma_f32_16x16x32_bf16(V1[m4], PR[m4], dacc[1], 0, 0, 0);     \
  }                                                                                          \
  SB;

  LDV(VA0, VA1, PAr, 0)
  LDV(VB0, VB1, PBr, 1)
  MMV(VA0, VA1, PAr) LDV(VA0, VA1, PAr, 2)
  MMV(VB0, VB1, PBr) LDV(VB0, VB1, PBr, 3)
  MMV(VA0, VA1, PAr) LDV(VA0, VA1, PAr, 4)
  MMV(VB0, VB1, PBr) LDV(VB0, VB1, PBr, 5)
  MMV(VA0, VA1, PAr) LDV(VA0, VA1, PAr, 6)
  MMV(VB0, VB1, PBr) LDV(VB0, VB1, PBr, 7)
  MMV(VA0, VA1, PAr)
  MMV(VB0, VB1, PBr)
#undef LDV
#undef MMV
  __syncthreads();

  float* Osh = (float*)Psh;
  short* Osh2 = Psh + 4352;
#pragma unroll
  for (int i = 0; i < 2; i++) {
    int cob = wv * 32 + i * 16 + quad * 4;
#pragma unroll
    for (int r = 0; r < 4; r++) Osh[(cob + r) * 17 + l16] = dacc[i][r];
  }
  __syncthreads();
  float g = gamma[sidx[b]];
  {
    int co = t >> 1, j0 = (t & 1) * 8;
    const float* xr = xb + (co << 10) + n0 + j0;
    float4 xv0 = *(const float4*)xr;
    float4 xv1 = *(const float4*)(xr + 4);
    float xs[8] = {xv0.x, xv0.y, xv0.z, xv0.w, xv1.x, xv1.y, xv1.z, xv1.w};
#pragma unroll
    for (int j = 0; j < 8; j++) {
      int nl = j0 + j;
      float rs = 1.0f / (reds[nl] + reds[16 + nl] + reds[32 + nl] + reds[48 + nl]);
      Osh2[nl * 136 + co] = f2bf(g * Osh[co * 17 + nl] * rs + xs[j]);
    }
  }
  __syncthreads();
  {
    int nl = t >> 4, cg = t & 15;
    bf16x8 u = *(const bf16x8*)&Osh2[nl * 136 + cg * 8];
    int p = n0 + nl;
    int ih = p >> 5, iw = p & 31;
    *(bf16x8*)(ybf + ((size_t)b * 1156 + (ih + 1) * 34 + (iw + 1)) * 128 + cg * 8) = u;
  }
}

// ---------------------------------------------------------------------------
// conv2 NEW: LDS-staged MFMA GEMM. grid (B, 32): y = ne(0..7: 2 oh-rows, 32px)
// + 8*cog(0..3: 64 co). Block stages its 6 padded input rows (52KB, XOR-
// swizzled vs bank conflicts) in ONE burst (13 float4/thread -> deep MLP),
// then MFMA from LDS with linear weight stream from L2. Norm de-fused.
__global__ __launch_bounds__(256, 2) void k_conv2n(
    const unsigned short* __restrict__ ybf, const unsigned short* __restrict__ wr,
    const int* __restrict__ sidx, float* __restrict__ x2) {
  __shared__ __align__(16) unsigned short Xs[26624];  // 53,248 B (52,224 used)
  const int t = threadIdx.x;
  const int b = blockIdx.x;
  const int y = blockIdx.y;
  const int ne = y & 7;   // oh in [2ne, 2ne+2)
  const int cog = y >> 3; // co base cog*64
  const int s = sidx[b];
  const int lane = t & 63, wv = t >> 6;
  const int quad = lane >> 4, l16 = lane & 15;

  // ---- one-shot burst stage: padded rows [4ne, 4ne+6) ----
  const unsigned short* gb = ybf + ((size_t)b * 1156 + 4 * ne * 34) * 128;
  {
    float4 v[13];
#pragma unroll
    for (int i = 0; i < 13; i++) v[i] = *(const float4*)(gb + (i * 256 + t) * 8);
#pragma unroll
    for (int i = 0; i < 13; i++) {
      int ba = (i * 256 + t) * 16;
      int sw = ba ^ (((ba >> 9) & 7) << 4);
      *(float4*)((char*)Xs + sw) = v[i];
    }
  }
  __syncthreads();

  // ---- MFMA from LDS; weights streamed (linear, L2-resident) ----
  const int co0w = cog * 64 + wv * 16;
  const unsigned short* ap = wr + ((size_t)(s * 256 + co0w + l16)) * 2048 + quad * 8;
  f32x4 acc[2];
  acc[0] = (f32x4){0.f, 0.f, 0.f, 0.f};
  acc[1] = (f32x4){0.f, 0.f, 0.f, 0.f};

#pragma unroll
  for (int kc = 0; kc < 64; kc++) {
    const int tap = kc >> 2;
    const int cio = (kc & 3) * 32 + quad * 8;
    const int kh = tap >> 2, kw = tap & 3;
    bf16x8 af = *(const bf16x8*)(ap + kc * 32);
#pragma unroll
    for (int nt = 0; nt < 2; nt++) {
      int lr = 2 * nt + kh;            // local padded row (0..5)
      int col = 2 * l16 + kw;          // padded col (0..33)
      int ba = ((lr * 34 + col) * 128 + cio) * 2;
      int sw = ba ^ (((ba >> 9) & 7) << 4);
      bf16x8 bv = *(const bf16x8*)((const char*)Xs + sw);
      acc[nt] = __builtin_amdgcn_mfma_f32_16x16x32_bf16(af, bv, acc[nt], 0, 0, 0);
    }
  }

#pragma unroll
  for (int nt = 0; nt < 2; nt++) {
    int p = ne * 32 + nt * 16 + l16;
#pragma unroll
    for (int r = 0; r < 4; r++)
      x2[((size_t)b * 256 + co0w + quad * 4 + r) * 256 + p] = acc[nt][r];
  }
}

// ---------------------------------------------------------------------------
// head: partial conv via LDS + atomicAdd (out pre-initialized with bias)
__global__ __launch_bounds__(256) void k_head_part(
    const float* __restrict__ x2, const float* __restrict__ wh,
    const int* __restrict__ sidx, float* __restrict__ out) {
  __shared__ float Xs[32 * 256];
  __shared__ float Wsh[512];
  const int t = threadIdx.x;
  const int b = blockIdx.x, cc = blockIdx.y;
  const int s = sidx[b];
  const float* xp = x2 + ((size_t)b * 256 + cc * 32) * 256;
#pragma unroll
  for (int i = 0; i < 32; i++) Xs[i * 256 + t] = xp[i * 256 + t];
#pragma unroll
  for (int i = 0; i < 2; i++) {
    int idx = i * 256 + t;
    Wsh[idx] = wh[s * 4096 + cc * 512 + idx];
  }
  __syncthreads();
  if (t < 225) {
    int oh = t / 15, ow = t % 15;
    float acc = 0.0f;
    for (int ci = 0; ci < 32; ci++) {
      const float* xr = Xs + ci * 256;
      const float* wr = Wsh + ci * 16;
#pragma unroll
      for (int kh = 0; kh < 4; kh++) {
        int ih = oh - 1 + kh;
        if ((unsigned)ih >= 16u) continue;
#pragma unroll
        for (int kw = 0; kw < 4; kw++) {
          int iw = ow - 1 + kw;
          if ((unsigned)iw >= 16u) continue;
          acc += wr[kh * 4 + kw] * xr[(ih << 4) + iw];
        }
      }
    }
    atomicAdd(out + b * 225 + t, acc);
  }
}

// ---------------------------------------------------------------------------
extern "C" void kernel_launch(void* const* d_in, const int* in_sizes, int n_in,
                              void* d_out, int out_size, void* d_ws, size_t ws_size,
                              hipStream_t stream) {
  const float* img = (const float*)d_in[0];
  const int* sidx = (const int*)d_in[1];
  const float* w0 = (const float*)d_in[2];
  const float* b0 = (const float*)d_in[3];
  const float* w1 = (const float*)d_in[4];
  const float* w2 = (const float*)d_in[6];
  const float* wq = (const float*)d_in[8];
  const float* bq = (const float*)d_in[9];
  const float* wk = (const float*)d_in[10];
  const float* bk = (const float*)d_in[11];
  const float* wv = (const float*)d_in[12];
  const float* bv = (const float*)d_in[13];
  const float* gamma = (const float*)d_in[14];
  const float* wh = (const float*)d_in[15];
  const float* bh = (const float*)d_in[16];
  float* out = (float*)d_out;

  float* ws = (float*)d_ws;
  unsigned short* x0t = (unsigned short*)(ws);            // padded 66x66: 16*4356*64 shorts
  float* x1 = ws + 2359296;                               // [2.25M,4.25M)
  float* q = ws + 4456448;                                // [4.25M,4.5M)
  float* k = ws + 4718592;                                // [4.5M,4.75M)
  unsigned short* vpk = (unsigned short*)(ws + 4980736);  // [4.75M,5.75M)
  unsigned short* ybf = (unsigned short*)(ws + 6029312);  // padded 34x34: 16*1156*128 shorts
  float* x2 = ws + 7340032;                               // [7M,8M)
  unsigned short* wr1 = (unsigned short*)(ws + 8912896);  // [8.5M,8.75M)
  unsigned short* wr2 = (unsigned short*)(ws + 9175040);  // [8.75M,9.75M)

  const int B = 16;

  k_repack_all<<<14613, 256, 0, stream>>>(w1, wr1, w2, wr2, bh, sidx, out, x0t, ybf,
                                          img, w0, b0);
  k_conv1<<<dim3(B, 32), 256, 0, stream>>>(x0t, wr1, sidx, x1);
  k_inorm<1024><<<B * 128, 256, 0, stream>>>(x1);
  k_proj_qkv<<<dim3(B, 40), 256, 0, stream>>>(x1, wq, bq, wk, bk, wv, bv, sidx, q, k, vpk);
  k_attn<<<B * 64, 256, 0, stream>>>(q, k, vpk, x1, gamma, sidx, ybf);
  k_conv2n<<<dim3(B, 32), 256, 0, stream>>>(ybf, wr2, sidx, x2);
  k_inormw<256><<<1024, 256, 0, stream>>>(x2);
  k_head_part<<<dim3(B, 8), 256, 0, stream>>>(x2, wh, sidx, out);
}

// Round 9
// 206.514 us; speedup vs baseline: 1.3179x; 1.0871x over previous
//
#include <hip/hip_runtime.h>

#define LRELU(x) ((x) > 0.0f ? (x) : 0.2f * (x))
#define SB __builtin_amdgcn_sched_barrier(0)

typedef short bf16x8 __attribute__((ext_vector_type(8)));
typedef short bf16x4 __attribute__((ext_vector_type(4)));
typedef float f32x4 __attribute__((ext_vector_type(4)));

__device__ __forceinline__ short f2bf(float f) {
  union { float f; unsigned u; } x{f};
  return (short)((x.u + 0x7FFF + ((x.u >> 16) & 1)) >> 16);
}

// ---------------------------------------------------------------------------
// fused prologue: weight repack (coalesced reads) + head-bias out init +
// border zeroing + conv0 (blocks >= 10517).
__global__ __launch_bounds__(256) void k_repack_all(
    const float* __restrict__ w1, unsigned short* __restrict__ wr1,
    const float* __restrict__ w2, unsigned short* __restrict__ wr2,
    const float* __restrict__ bh, const int* __restrict__ sidx,
    float* __restrict__ out, unsigned short* __restrict__ x0t,
    unsigned short* __restrict__ ybf, const float* __restrict__ img,
    const float* __restrict__ w0, const float* __restrict__ b0) {
  __shared__ float Ish[4 * 34];
  if (blockIdx.x >= 10517) {
    // ---- conv0 segment: img (B,1,128,128) -> x0t padded 66x66 NHWC bf16
    const int t = threadIdx.x;
    const int q = blockIdx.x - 10517;
    const int b = q >> 8, py = q & 255;
    const int oh = py >> 2, owb = (py & 3) << 4;
    const int s = sidx[b];
    const float* ip = img + (size_t)b * 16384;
    if (t < 136) {
      int r = t / 34, c = t % 34;
      int ih = 2 * oh - 1 + r, iw = 2 * owb - 1 + c;
      Ish[t] = ((unsigned)ih < 128u && (unsigned)iw < 128u) ? ip[ih * 128 + iw] : 0.f;
    }
    const int co = t & 63, ps = t >> 6;
    float wreg[16];
    const float* wp = w0 + (s * 64 + co) * 16;
#pragma unroll
    for (int i = 0; i < 16; i++) wreg[i] = wp[i];
    float bb = b0[s * 64 + co];
    __syncthreads();
    unsigned short* op = x0t + ((size_t)b * 4356 + (oh + 1) * 66 + (owb + 1)) * 64 + co;
#pragma unroll
    for (int j = 0; j < 4; j++) {
      int pl = ps * 4 + j;
      float acc = bb;
#pragma unroll
      for (int kh = 0; kh < 4; kh++)
#pragma unroll
        for (int kw = 0; kw < 4; kw++)
          acc += wreg[kh * 4 + kw] * Ish[kh * 34 + pl * 2 + kw];
      acc = LRELU(acc);
      op[pl * 64] = (unsigned short)f2bf(acc);
    }
    return;
  }
  int idx = blockIdx.x * 256 + threadIdx.x;
  if (idx < 524288) {
    // w1: src-ordered. idx = ((s*128+co)*64+ci)*16+tap
    int tap = idx & 15;
    int rest = idx >> 4;
    int ci = rest & 63, sco = rest >> 6;
    wr1[(size_t)sco * 1024 + tap * 64 + ci] = (unsigned short)f2bf(w1[idx]);
    return;
  } else if (idx < 2621440) {
    // w2: src-ordered. i = ((s*256+co)*128+ci)*16+tap
    int i = idx - 524288;
    int tap = i & 15;
    int rest = i >> 4;
    int ci = rest & 127, sco = rest >> 7;
    wr2[(size_t)sco * 2048 + tap * 128 + ci] = (unsigned short)f2bf(w2[i]);
    return;
  } else if (idx < 2625040) {
    int i = idx - 2621440;
    if (i < 3600) out[i] = bh[sidx[i / 225]];
    return;
  } else if (idx < 2658320) {
    // zero x0t border
    int i = idx - 2625040;
    int b = i / 2080, r = i % 2080;
    int pix = r >> 3, sub = r & 7;
    int row, col;
    if (pix < 66) { row = 0; col = pix; }
    else if (pix < 132) { row = 65; col = pix - 66; }
    else { int qq = pix - 132; row = 1 + (qq >> 1); col = (qq & 1) * 65; }
    bf16x8 z = {0, 0, 0, 0, 0, 0, 0, 0};
    *(bf16x8*)(x0t + ((size_t)b * 4356 + row * 66 + col) * 64 + sub * 8) = z;
    return;
  } else {
    // zero ybf border
    int i = idx - 2658320;
    if (i >= 33792) return;
    int b = i / 2112, r = i % 2112;
    int pix = r >> 4, sub = r & 15;
    int row, col;
    if (pix < 34) { row = 0; col = pix; }
    else if (pix < 68) { row = 33; col = pix - 34; }
    else { int qq = pix - 68; row = 1 + (qq >> 1); col = (qq & 1) * 33; }
    bf16x8 z = {0, 0, 0, 0, 0, 0, 0, 0};
    *(bf16x8*)(ybf + ((size_t)b * 1156 + row * 34 + col) * 128 + sub * 8) = z;
    return;
  }
}

// ---------------------------------------------------------------------------
// conv1 NEW: LDS-staged MFMA GEMM (conv2n structure ported). grid (B, 32):
// y = ne(0..15: 2 oh-rows = 64px) | cog(0..1)<<4 (64 co). Block burst-stages
// 6 padded input rows (6x66x64 bf16 = 50,688B, XOR-swizzled), then MFMA from
// LDS with linear weight stream. Same kc order as old conv1 -> bitwise equal.
__global__ __launch_bounds__(256, 2) void k_conv1n(
    const unsigned short* __restrict__ x0t, const unsigned short* __restrict__ wr,
    const int* __restrict__ sidx, float* __restrict__ x1) {
  __shared__ __align__(16) unsigned short Xs[26624];  // 53,248 B (50,688 used)
  const int t = threadIdx.x;
  const int b = blockIdx.x;
  const int y = blockIdx.y;
  const int ne = y & 15;   // output rows [2ne, 2ne+2)
  const int cog = y >> 4;  // co base cog*64
  const int s = sidx[b];
  const int lane = t & 63, wv = t >> 6;
  const int quad = lane >> 4, l16 = lane & 15;

  // ---- one-shot burst stage: padded rows [4ne, 4ne+6) of 66x64 bf16 ----
  const unsigned short* gb = x0t + ((size_t)b * 4356 + 4 * ne * 66) * 64;
  {
    float4 v[13];
#pragma unroll
    for (int i = 0; i < 13; i++) v[i] = *(const float4*)(gb + (i * 256 + t) * 8);
#pragma unroll
    for (int i = 0; i < 13; i++) {
      int ba = (i * 256 + t) * 16;
      int sw = ba ^ (((ba >> 9) & 7) << 4);
      *(float4*)((char*)Xs + sw) = v[i];
    }
  }
  __syncthreads();

  // ---- MFMA from LDS; weights streamed (linear, L2-resident) ----
  const int co0w = cog * 64 + wv * 16;
  const unsigned short* ap = wr + ((size_t)(s * 128 + co0w + l16)) * 1024 + quad * 8;
  f32x4 acc[4];
#pragma unroll
  for (int nt = 0; nt < 4; nt++) acc[nt] = (f32x4){0.f, 0.f, 0.f, 0.f};

#pragma unroll
  for (int kc = 0; kc < 32; kc++) {
    const int tap = kc >> 1;
    const int cio = (kc & 1) * 32 + quad * 8;
    const int kh = tap >> 2, kw = tap & 3;
    bf16x8 af = *(const bf16x8*)(ap + kc * 32);
#pragma unroll
    for (int nt = 0; nt < 4; nt++) {
      int lr = 2 * (nt >> 1) + kh;               // local padded row (0..5)
      int col = 2 * ((nt & 1) * 16 + l16) + kw;  // padded col (0..65)
      int ba = ((lr * 66 + col) * 64 + cio) * 2;
      int sw = ba ^ (((ba >> 9) & 7) << 4);
      bf16x8 bv = *(const bf16x8*)((const char*)Xs + sw);
      acc[nt] = __builtin_amdgcn_mfma_f32_16x16x32_bf16(af, bv, acc[nt], 0, 0, 0);
    }
  }

#pragma unroll
  for (int nt = 0; nt < 4; nt++) {
    int p = ne * 64 + (nt >> 1) * 32 + (nt & 1) * 16 + l16;
#pragma unroll
    for (int r = 0; r < 4; r++)
      x1[((size_t)b * 128 + co0w + quad * 4 + r) * 1024 + p] = acc[nt][r];
  }
}

// ---------------------------------------------------------------------------
// in-place instance norm (+leaky), NPIX per (b,c) — proven block version
template <int NPIX>
__global__ __launch_bounds__(256) void k_inorm(float* __restrict__ x) {
  constexpr int E = NPIX / 256;
  float* p = x + (size_t)blockIdx.x * NPIX;
  const int t = threadIdx.x;
  float v[E];
  float sum = 0.f, sq = 0.f;
#pragma unroll
  for (int i = 0; i < E; i++) {
    v[i] = p[i * 256 + t];
    sum += v[i];
    sq += v[i] * v[i];
  }
#pragma unroll
  for (int o = 32; o > 0; o >>= 1) {
    sum += __shfl_down(sum, o, 64);
    sq += __shfl_down(sq, o, 64);
  }
  __shared__ float red[8];
  int wid = t >> 6;
  if ((t & 63) == 0) {
    red[wid] = sum;
    red[4 + wid] = sq;
  }
  __syncthreads();
  float S = red[0] + red[1] + red[2] + red[3];
  float SQ = red[4] + red[5] + red[6] + red[7];
  float m = S * (1.0f / NPIX);
  float var = SQ * (1.0f / NPIX) - m * m;
  float inv = rsqrtf(var + 1e-5f);
#pragma unroll
  for (int i = 0; i < E; i++) p[i * 256 + t] = LRELU((v[i] - m) * inv);
}

// ---------------------------------------------------------------------------
// instance norm (+leaky): one wave per (b,c) row, float4 loads, no barriers.
template <int NPIX>
__global__ __launch_bounds__(256) void k_inormw(float* __restrict__ x) {
  constexpr int E = NPIX / 256;  // float4s per lane
  const int wv = threadIdx.x >> 6, lane = threadIdx.x & 63;
  const size_t row = (size_t)blockIdx.x * 4 + wv;
  float4* p = (float4*)(x + row * NPIX);
  float4 v[E];
#pragma unroll
  for (int i = 0; i < E; i++) v[i] = p[i * 64 + lane];
  float sum = 0.f, sq = 0.f;
#pragma unroll
  for (int i = 0; i < E; i++) {
    sum += v[i].x + v[i].y + v[i].z + v[i].w;
    sq += v[i].x * v[i].x + v[i].y * v[i].y + v[i].z * v[i].z + v[i].w * v[i].w;
  }
#pragma unroll
  for (int o = 32; o > 0; o >>= 1) {
    sum += __shfl_xor(sum, o, 64);
    sq += __shfl_xor(sq, o, 64);
  }
  float m = sum * (1.0f / NPIX);
  float var = sq * (1.0f / NPIX) - m * m;
  float inv = rsqrtf(var + 1e-5f);
#pragma unroll
  for (int i = 0; i < E; i++) {
    v[i].x = LRELU((v[i].x - m) * inv);
    v[i].y = LRELU((v[i].y - m) * inv);
    v[i].z = LRELU((v[i].z - m) * inv);
    v[i].w = LRELU((v[i].w - m) * inv);
    p[i * 64 + lane] = v[i];
  }
}

// ---------------------------------------------------------------------------
// fused q/k/v 1x1 projections. grid (B, 40): y<4 q, y<8 k, else v (chunked bf16)
__global__ __launch_bounds__(256) void k_proj_qkv(
    const float* __restrict__ xin, const float* __restrict__ wq,
    const float* __restrict__ bq, const float* __restrict__ wk,
    const float* __restrict__ bk, const float* __restrict__ wv,
    const float* __restrict__ bv, const int* __restrict__ sidx,
    float* __restrict__ q, float* __restrict__ kout, unsigned short* __restrict__ vpk) {
  __shared__ float xsh[32 * 256];
  __shared__ float wsh[16 * 32];
  const int t = threadIdx.x;
  const int b = blockIdx.x;
  const int y = blockIdx.y;
  const int s = sidx[b];
  const int cg = t >> 6, ng = t & 63;
  const float* w;
  const float* bias;
  int co0, nn0, CO;
  if (y < 8) {
    w = (y < 4) ? wq : wk;
    bias = (y < 4) ? bq : bk;
    co0 = 0;
    nn0 = (y & 3) * 256;
    CO = 16;
  } else {
    w = wv;
    bias = bv;
    co0 = ((y - 8) >> 2) * 16;
    nn0 = ((y - 8) & 3) * 256;
    CO = 128;
  }
  const float* xb = xin + (size_t)b * 128 * 1024;
  float4 acc4[4];
#pragma unroll
  for (int c = 0; c < 4; c++) {
    float bb = bias[s * CO + co0 + cg * 4 + c];
    acc4[c] = make_float4(bb, bb, bb, bb);
  }
  for (int cc = 0; cc < 4; cc++) {
#pragma unroll
    for (int k = 0; k < 8; k++) {
      int id = t + (k << 8);
      int ci = id >> 6, nf = id & 63;
      ((float4*)xsh)[id] = ((const float4*)(xb + (cc * 32 + ci) * 1024 + nn0))[nf];
    }
    if (t < 128)
      ((float4*)wsh)[t] =
          ((const float4*)(w + ((size_t)(s * CO + co0 + (t >> 3))) * 128 + cc * 32))[t & 7];
    __syncthreads();
#pragma unroll
    for (int ci4 = 0; ci4 < 8; ci4++) {
      float4 wvv[4], xv[4];
#pragma unroll
      for (int c = 0; c < 4; c++) wvv[c] = ((const float4*)wsh)[(cg * 4 + c) * 8 + ci4];
#pragma unroll
      for (int i = 0; i < 4; i++) xv[i] = ((const float4*)xsh)[(ci4 * 4 + i) * 64 + ng];
#pragma unroll
      for (int c = 0; c < 4; c++)
#pragma unroll
        for (int i = 0; i < 4; i++) {
          float wvc = i == 0 ? wvv[c].x : i == 1 ? wvv[c].y : i == 2 ? wvv[c].z : wvv[c].w;
          acc4[c].x += wvc * xv[i].x;
          acc4[c].y += wvc * xv[i].y;
          acc4[c].z += wvc * xv[i].z;
          acc4[c].w += wvc * xv[i].w;
        }
    }
    __syncthreads();
  }
  if (y < 8) {
    float* out = (y < 4) ? q : kout;
#pragma unroll
    for (int c = 0; c < 4; c++)
      ((float4*)(out + ((size_t)b * 16 + cg * 4 + c) * 1024 + nn0))[ng] = acc4[c];
  } else {
    int n = nn0 + ng * 4;
#pragma unroll
    for (int c = 0; c < 4; c++) {
      int co = co0 + cg * 4 + c;
      bf16x4 u;
      u[0] = f2bf(acc4[c].x);
      u[1] = f2bf(acc4[c].y);
      u[2] = f2bf(acc4[c].z);
      u[3] = f2bf(acc4[c].w);
      *(bf16x4*)(vpk + (((size_t)b * 32 + (n >> 5)) * 128 + co) * 32 + (n & 31)) = u;
    }
  }
}

// ---------------------------------------------------------------------------
// fused self-attention — round-5 proven version (SB ping-pong, (256,2))
__global__ __launch_bounds__(256, 2) void k_attn(
    const float* __restrict__ q, const float* __restrict__ k,
    const unsigned short* __restrict__ vpk, const float* __restrict__ x1,
    const float* __restrict__ gamma, const int* __restrict__ sidx,
    unsigned short* __restrict__ ybf) {
  __shared__ __align__(16) short Psh[16 * 1032];
  __shared__ float qsh[256];
  __shared__ float redm[64], reds[64];
  const int t = threadIdx.x;
  const int b = blockIdx.x >> 6;
  const int n0 = (blockIdx.x & 63) << 4;
  const int lane = t & 63, wv = t >> 6;
  const int quad = lane >> 4, l16 = lane & 15;
  const float* qb = q + (size_t)b * 16 * 1024;
  const float* kb = k + (size_t)b * 16 * 1024;
  const float* xb = x1 + (size_t)b * 128 * 1024;

  qsh[t] = qb[((t >> 4) << 10) + n0 + (t & 15)];
  __syncthreads();

  float acc[4][16];
#pragma unroll
  for (int j = 0; j < 4; j++)
#pragma unroll
    for (int nl = 0; nl < 16; nl++) acc[j][nl] = 0.0f;

  float4 KA[4], KB[4];
#define LDK(BUF, G)                                                       \
  _Pragma("unroll") for (int c4 = 0; c4 < 4; c4++)                        \
      BUF[c4] = *(const float4*)(kb + ((((G) * 4 + c4)) << 10) + 4 * t);  \
  SB;
#define MMK(BUF, G)                                                                         \
  _Pragma("unroll") for (int c4 = 0; c4 < 4; c4++) {                                        \
    const float* qr = qsh + ((G) * 4 + c4) * 16;                                            \
    _Pragma("unroll") for (int j = 0; j < 4; j++) {                                         \
      float kk = j == 0 ? BUF[c4].x : j == 1 ? BUF[c4].y : j == 2 ? BUF[c4].z : BUF[c4].w;  \
      _Pragma("unroll") for (int nl = 0; nl < 16; nl++) acc[j][nl] += kk * qr[nl];          \
    }                                                                                       \
  }                                                                                         \
  SB;

  LDK(KA, 0)
  LDK(KB, 1)
  MMK(KA, 0) LDK(KA, 2)
  MMK(KB, 1) LDK(KB, 3)
  MMK(KA, 2)
  MMK(KB, 3)
#undef LDK
#undef MMK

  float lmax[16];
#pragma unroll
  for (int nl = 0; nl < 16; nl++)
    lmax[nl] = fmaxf(fmaxf(acc[0][nl], acc[1][nl]), fmaxf(acc[2][nl], acc[3][nl]));
#pragma unroll
  for (int o = 32; o > 0; o >>= 1)
#pragma unroll
    for (int nl = 0; nl < 16; nl++) lmax[nl] = fmaxf(lmax[nl], __shfl_xor(lmax[nl], o, 64));
  if (lane == 0)
#pragma unroll
    for (int nl = 0; nl < 16; nl++) redm[wv * 16 + nl] = lmax[nl];
  __syncthreads();
#pragma unroll
  for (int nl = 0; nl < 16; nl++)
    lmax[nl] = fmaxf(fmaxf(redm[nl], redm[16 + nl]), fmaxf(redm[32 + nl], redm[48 + nl]));
  float lsum[16];
#pragma unroll
  for (int nl = 0; nl < 16; nl++) lsum[nl] = 0.0f;
#pragma unroll
  for (int j = 0; j < 4; j++)
#pragma unroll
    for (int nl = 0; nl < 16; nl++) {
      float e = __expf(acc[j][nl] - lmax[nl]);
      acc[j][nl] = e;
      lsum[nl] += e;
    }
#pragma unroll
  for (int o = 32; o > 0; o >>= 1)
#pragma unroll
    for (int nl = 0; nl < 16; nl++) lsum[nl] += __shfl_xor(lsum[nl], o, 64);
  if (lane == 0)
#pragma unroll
    for (int nl = 0; nl < 16; nl++) reds[wv * 16 + nl] = lsum[nl];
#pragma unroll
  for (int nl = 0; nl < 16; nl++) {
    bf16x4 pv;
    pv[0] = f2bf(acc[0][nl]);
    pv[1] = f2bf(acc[1][nl]);
    pv[2] = f2bf(acc[2][nl]);
    pv[3] = f2bf(acc[3][nl]);
    *(bf16x4*)&Psh[nl * 1032 + 4 * t] = pv;
  }
  __syncthreads();

  const unsigned short* vp =
      vpk + ((size_t)b * 32 * 128 + (size_t)(wv * 32 + l16)) * 32 + quad * 8;
  const short* prow = Psh + l16 * 1032 + quad * 8;
  f32x4 dacc[2];
  dacc[0] = (f32x4){0.f, 0.f, 0.f, 0.f};
  dacc[1] = (f32x4){0.f, 0.f, 0.f, 0.f};

  bf16x8 VA0[4], VA1[4], PAr[4];
  bf16x8 VB0[4], VB1[4], PBr[4];
#define LDV(V0, V1, PR, G)                                \
  _Pragma("unroll") for (int m4 = 0; m4 < 4; m4++) {      \
    int mt = (G) * 4 + m4;                                \
    V0[m4] = *(const bf16x8*)(vp + mt * 4096);            \
    V1[m4] = *(const bf16x8*)(vp + 512 + mt * 4096);      \
    PR[m4] = *(const bf16x8*)(prow + mt * 32);            \
  }                                                       \
  SB;
#define MMV(V0, V1, PR)                                                                      \
  _Pragma("unroll") for (int m4 = 0; m4 < 4; m4++) {                                         \
    dacc[0] = __builtin_amdgcn_mfma_f32_16x16x32_bf16(V0[m4], PR[m4], dacc[0], 0, 0, 0);     \
    dacc[1] = __builtin_amdgcn_mfma_f32_16x16x32_bf16(V1[m4], PR[m4], dacc[1], 0, 0, 0);     \
  }                                                                                          \
  SB;

  LDV(VA0, VA1, PAr, 0)
  LDV(VB0, VB1, PBr, 1)
  MMV(VA0, VA1, PAr) LDV(VA0, VA1, PAr, 2)
  MMV(VB0, VB1, PBr) LDV(VB0, VB1, PBr, 3)
  MMV(VA0, VA1, PAr) LDV(VA0, VA1, PAr, 4)
  MMV(VB0, VB1, PBr) LDV(VB0, VB1, PBr, 5)
  MMV(VA0, VA1, PAr) LDV(VA0, VA1, PAr, 6)
  MMV(VB0, VB1, PBr) LDV(VB0, VB1, PBr, 7)
  MMV(VA0, VA1, PAr)
  MMV(VB0, VB1, PBr)
#undef LDV
#undef MMV
  __syncthreads();

  float* Osh = (float*)Psh;
  short* Osh2 = Psh + 4352;
#pragma unroll
  for (int i = 0; i < 2; i++) {
    int cob = wv * 32 + i * 16 + quad * 4;
#pragma unroll
    for (int r = 0; r < 4; r++) Osh[(cob + r) * 17 + l16] = dacc[i][r];
  }
  __syncthreads();
  float g = gamma[sidx[b]];
  {
    int co = t >> 1, j0 = (t & 1) * 8;
    const float* xr = xb + (co << 10) + n0 + j0;
    float4 xv0 = *(const float4*)xr;
    float4 xv1 = *(const float4*)(xr + 4);
    float xs[8] = {xv0.x, xv0.y, xv0.z, xv0.w, xv1.x, xv1.y, xv1.z, xv1.w};
#pragma unroll
    for (int j = 0; j < 8; j++) {
      int nl = j0 + j;
      float rs = 1.0f / (reds[nl] + reds[16 + nl] + reds[32 + nl] + reds[48 + nl]);
      Osh2[nl * 136 + co] = f2bf(g * Osh[co * 17 + nl] * rs + xs[j]);
    }
  }
  __syncthreads();
  {
    int nl = t >> 4, cg = t & 15;
    bf16x8 u = *(const bf16x8*)&Osh2[nl * 136 + cg * 8];
    int p = n0 + nl;
    int ih = p >> 5, iw = p & 31;
    *(bf16x8*)(ybf + ((size_t)b * 1156 + (ih + 1) * 34 + (iw + 1)) * 128 + cg * 8) = u;
  }
}

// ---------------------------------------------------------------------------
// conv2: LDS-staged MFMA GEMM (proven round 8). grid (B, 32).
__global__ __launch_bounds__(256, 2) void k_conv2n(
    const unsigned short* __restrict__ ybf, const unsigned short* __restrict__ wr,
    const int* __restrict__ sidx, float* __restrict__ x2) {
  __shared__ __align__(16) unsigned short Xs[26624];  // 53,248 B (52,224 used)
  const int t = threadIdx.x;
  const int b = blockIdx.x;
  const int y = blockIdx.y;
  const int ne = y & 7;   // oh in [2ne, 2ne+2)
  const int cog = y >> 3; // co base cog*64
  const int s = sidx[b];
  const int lane = t & 63, wv = t >> 6;
  const int quad = lane >> 4, l16 = lane & 15;

  // ---- one-shot burst stage: padded rows [4ne, 4ne+6) ----
  const unsigned short* gb = ybf + ((size_t)b * 1156 + 4 * ne * 34) * 128;
  {
    float4 v[13];
#pragma unroll
    for (int i = 0; i < 13; i++) v[i] = *(const float4*)(gb + (i * 256 + t) * 8);
#pragma unroll
    for (int i = 0; i < 13; i++) {
      int ba = (i * 256 + t) * 16;
      int sw = ba ^ (((ba >> 9) & 7) << 4);
      *(float4*)((char*)Xs + sw) = v[i];
    }
  }
  __syncthreads();

  // ---- MFMA from LDS; weights streamed (linear, L2-resident) ----
  const int co0w = cog * 64 + wv * 16;
  const unsigned short* ap = wr + ((size_t)(s * 256 + co0w + l16)) * 2048 + quad * 8;
  f32x4 acc[2];
  acc[0] = (f32x4){0.f, 0.f, 0.f, 0.f};
  acc[1] = (f32x4){0.f, 0.f, 0.f, 0.f};

#pragma unroll
  for (int kc = 0; kc < 64; kc++) {
    const int tap = kc >> 2;
    const int cio = (kc & 3) * 32 + quad * 8;
    const int kh = tap >> 2, kw = tap & 3;
    bf16x8 af = *(const bf16x8*)(ap + kc * 32);
#pragma unroll
    for (int nt = 0; nt < 2; nt++) {
      int lr = 2 * nt + kh;            // local padded row (0..5)
      int col = 2 * l16 + kw;          // padded col (0..33)
      int ba = ((lr * 34 + col) * 128 + cio) * 2;
      int sw = ba ^ (((ba >> 9) & 7) << 4);
      bf16x8 bv = *(const bf16x8*)((const char*)Xs + sw);
      acc[nt] = __builtin_amdgcn_mfma_f32_16x16x32_bf16(af, bv, acc[nt], 0, 0, 0);
    }
  }

#pragma unroll
  for (int nt = 0; nt < 2; nt++) {
    int p = ne * 32 + nt * 16 + l16;
#pragma unroll
    for (int r = 0; r < 4; r++)
      x2[((size_t)b * 256 + co0w + quad * 4 + r) * 256 + p] = acc[nt][r];
  }
}

// ---------------------------------------------------------------------------
// head: partial conv via LDS + atomicAdd (out pre-initialized with bias)
__global__ __launch_bounds__(256) void k_head_part(
    const float* __restrict__ x2, const float* __restrict__ wh,
    const int* __restrict__ sidx, float* __restrict__ out) {
  __shared__ float Xs[32 * 256];
  __shared__ float Wsh[512];
  const int t = threadIdx.x;
  const int b = blockIdx.x, cc = blockIdx.y;
  const int s = sidx[b];
  const float* xp = x2 + ((size_t)b * 256 + cc * 32) * 256;
#pragma unroll
  for (int i = 0; i < 32; i++) Xs[i * 256 + t] = xp[i * 256 + t];
#pragma unroll
  for (int i = 0; i < 2; i++) {
    int idx = i * 256 + t;
    Wsh[idx] = wh[s * 4096 + cc * 512 + idx];
  }
  __syncthreads();
  if (t < 225) {
    int oh = t / 15, ow = t % 15;
    float acc = 0.0f;
    for (int ci = 0; ci < 32; ci++) {
      const float* xr = Xs + ci * 256;
      const float* wr = Wsh + ci * 16;
#pragma unroll
      for (int kh = 0; kh < 4; kh++) {
        int ih = oh - 1 + kh;
        if ((unsigned)ih >= 16u) continue;
#pragma unroll
        for (int kw = 0; kw < 4; kw++) {
          int iw = ow - 1 + kw;
          if ((unsigned)iw >= 16u) continue;
          acc += wr[kh * 4 + kw] * xr[(ih << 4) + iw];
        }
      }
    }
    atomicAdd(out + b * 225 + t, acc);
  }
}

// ---------------------------------------------------------------------------
extern "C" void kernel_launch(void* const* d_in, const int* in_sizes, int n_in,
                              void* d_out, int out_size, void* d_ws, size_t ws_size,
                              hipStream_t stream) {
  const float* img = (const float*)d_in[0];
  const int* sidx = (const int*)d_in[1];
  const float* w0 = (const float*)d_in[2];
  const float* b0 = (const float*)d_in[3];
  const float* w1 = (const float*)d_in[4];
  const float* w2 = (const float*)d_in[6];
  const float* wq = (const float*)d_in[8];
  const float* bq = (const float*)d_in[9];
  const float* wk = (const float*)d_in[10];
  const float* bk = (const float*)d_in[11];
  const float* wv = (const float*)d_in[12];
  const float* bv = (const float*)d_in[13];
  const float* gamma = (const float*)d_in[14];
  const float* wh = (const float*)d_in[15];
  const float* bh = (const float*)d_in[16];
  float* out = (float*)d_out;

  float* ws = (float*)d_ws;
  unsigned short* x0t = (unsigned short*)(ws);            // padded 66x66: 16*4356*64 shorts
  float* x1 = ws + 2359296;                               // [2.25M,4.25M)
  float* q = ws + 4456448;                                // [4.25M,4.5M)
  float* k = ws + 4718592;                                // [4.5M,4.75M)
  unsigned short* vpk = (unsigned short*)(ws + 4980736);  // [4.75M,5.75M)
  unsigned short* ybf = (unsigned short*)(ws + 6029312);  // padded 34x34: 16*1156*128 shorts
  float* x2 = ws + 7340032;                               // [7M,8M)
  unsigned short* wr1 = (unsigned short*)(ws + 8912896);  // [8.5M,8.75M)
  unsigned short* wr2 = (unsigned short*)(ws + 9175040);  // [8.75M,9.75M)

  const int B = 16;

  k_repack_all<<<14613, 256, 0, stream>>>(w1, wr1, w2, wr2, bh, sidx, out, x0t, ybf,
                                          img, w0, b0);
  k_conv1n<<<dim3(B, 32), 256, 0, stream>>>(x0t, wr1, sidx, x1);
  k_inorm<1024><<<B * 128, 256, 0, stream>>>(x1);
  k_proj_qkv<<<dim3(B, 40), 256, 0, stream>>>(x1, wq, bq, wk, bk, wv, bv, sidx, q, k, vpk);
  k_attn<<<B * 64, 256, 0, stream>>>(q, k, vpk, x1, gamma, sidx, ybf);
  k_conv2n<<<dim3(B, 32), 256, 0, stream>>>(ybf, wr2, sidx, x2);
  k_inormw<256><<<1024, 256, 0, stream>>>(x2);
  k_head_part<<<dim3(B, 8), 256, 0, stream>>>(x2, wh, sidx, out);
}

// Round 10
// 201.049 us; speedup vs baseline: 1.3537x; 1.0272x over previous
//
#include <hip/hip_runtime.h>

#define LRELU(x) ((x) > 0.0f ? (x) : 0.2f * (x))
#define SB __builtin_amdgcn_sched_barrier(0)

typedef short bf16x8 __attribute__((ext_vector_type(8)));
typedef short bf16x4 __attribute__((ext_vector_type(4)));
typedef float f32x4 __attribute__((ext_vector_type(4)));

__device__ __forceinline__ short f2bf(float f) {
  union { float f; unsigned u; } x{f};
  return (short)((x.u + 0x7FFF + ((x.u >> 16) & 1)) >> 16);
}

// ---------------------------------------------------------------------------
// fused prologue: weight repack (float4-vectorized coalesced reads) +
// head-bias out init + border zeroing + conv0 (blocks >= 2837).
// segments (threads): [0,131072) w1-vec4 | [..,655360) w2-vec4 |
// [..,658960) bias | [..,692240) x0t border | [..,726032) ybf border
__global__ __launch_bounds__(256) void k_repack_all(
    const float* __restrict__ w1, unsigned short* __restrict__ wr1,
    const float* __restrict__ w2, unsigned short* __restrict__ wr2,
    const float* __restrict__ bh, const int* __restrict__ sidx,
    float* __restrict__ out, unsigned short* __restrict__ x0t,
    unsigned short* __restrict__ ybf, const float* __restrict__ img,
    const float* __restrict__ w0, const float* __restrict__ b0) {
  __shared__ float Ish[4 * 34];
  if (blockIdx.x >= 2837) {
    // ---- conv0 segment: img (B,1,128,128) -> x0t padded 66x66 NHWC bf16
    const int t = threadIdx.x;
    const int q = blockIdx.x - 2837;
    const int b = q >> 8, py = q & 255;
    const int oh = py >> 2, owb = (py & 3) << 4;
    const int s = sidx[b];
    const float* ip = img + (size_t)b * 16384;
    if (t < 136) {
      int r = t / 34, c = t % 34;
      int ih = 2 * oh - 1 + r, iw = 2 * owb - 1 + c;
      Ish[t] = ((unsigned)ih < 128u && (unsigned)iw < 128u) ? ip[ih * 128 + iw] : 0.f;
    }
    const int co = t & 63, ps = t >> 6;
    float wreg[16];
    const float* wp = w0 + (s * 64 + co) * 16;
#pragma unroll
    for (int i = 0; i < 16; i++) wreg[i] = wp[i];
    float bb = b0[s * 64 + co];
    __syncthreads();
    unsigned short* op = x0t + ((size_t)b * 4356 + (oh + 1) * 66 + (owb + 1)) * 64 + co;
#pragma unroll
    for (int j = 0; j < 4; j++) {
      int pl = ps * 4 + j;
      float acc = bb;
#pragma unroll
      for (int kh = 0; kh < 4; kh++)
#pragma unroll
        for (int kw = 0; kw < 4; kw++)
          acc += wreg[kh * 4 + kw] * Ish[kh * 34 + pl * 2 + kw];
      acc = LRELU(acc);
      op[pl * 64] = (unsigned short)f2bf(acc);
    }
    return;
  }
  int idx = blockIdx.x * 256 + threadIdx.x;
  if (idx < 131072) {
    // w1 vec4: 4 consecutive taps, same (ci,sco)
    float4 v = *(const float4*)(w1 + (size_t)idx * 4);
    int base = idx * 4;
    int tap0 = base & 15;
    int rest = base >> 4;
    int ci = rest & 63, sco = rest >> 6;
    unsigned short* d = wr1 + (size_t)sco * 1024 + ci;
    d[(tap0 + 0) * 64] = (unsigned short)f2bf(v.x);
    d[(tap0 + 1) * 64] = (unsigned short)f2bf(v.y);
    d[(tap0 + 2) * 64] = (unsigned short)f2bf(v.z);
    d[(tap0 + 3) * 64] = (unsigned short)f2bf(v.w);
    return;
  } else if (idx < 655360) {
    // w2 vec4
    int i = idx - 131072;
    float4 v = *(const float4*)(w2 + (size_t)i * 4);
    int base = i * 4;
    int tap0 = base & 15;
    int rest = base >> 4;
    int ci = rest & 127, sco = rest >> 7;
    unsigned short* d = wr2 + (size_t)sco * 2048 + ci;
    d[(tap0 + 0) * 128] = (unsigned short)f2bf(v.x);
    d[(tap0 + 1) * 128] = (unsigned short)f2bf(v.y);
    d[(tap0 + 2) * 128] = (unsigned short)f2bf(v.z);
    d[(tap0 + 3) * 128] = (unsigned short)f2bf(v.w);
    return;
  } else if (idx < 658960) {
    int i = idx - 655360;
    if (i < 3600) out[i] = bh[sidx[i / 225]];
    return;
  } else if (idx < 692240) {
    // zero x0t border
    int i = idx - 658960;
    int b = i / 2080, r = i % 2080;
    int pix = r >> 3, sub = r & 7;
    int row, col;
    if (pix < 66) { row = 0; col = pix; }
    else if (pix < 132) { row = 65; col = pix - 66; }
    else { int qq = pix - 132; row = 1 + (qq >> 1); col = (qq & 1) * 65; }
    bf16x8 z = {0, 0, 0, 0, 0, 0, 0, 0};
    *(bf16x8*)(x0t + ((size_t)b * 4356 + row * 66 + col) * 64 + sub * 8) = z;
    return;
  } else {
    // zero ybf border
    int i = idx - 692240;
    if (i >= 33792) return;
    int b = i / 2112, r = i % 2112;
    int pix = r >> 4, sub = r & 15;
    int row, col;
    if (pix < 34) { row = 0; col = pix; }
    else if (pix < 68) { row = 33; col = pix - 34; }
    else { int qq = pix - 68; row = 1 + (qq >> 1); col = (qq & 1) * 33; }
    bf16x8 z = {0, 0, 0, 0, 0, 0, 0, 0};
    *(bf16x8*)(ybf + ((size_t)b * 1156 + row * 34 + col) * 128 + sub * 8) = z;
    return;
  }
}

// ---------------------------------------------------------------------------
// conv1: LDS-staged MFMA GEMM (proven round 9). grid (B, 32).
__global__ __launch_bounds__(256, 2) void k_conv1n(
    const unsigned short* __restrict__ x0t, const unsigned short* __restrict__ wr,
    const int* __restrict__ sidx, float* __restrict__ x1) {
  __shared__ __align__(16) unsigned short Xs[26624];  // 53,248 B (50,688 used)
  const int t = threadIdx.x;
  const int b = blockIdx.x;
  const int y = blockIdx.y;
  const int ne = y & 15;   // output rows [2ne, 2ne+2)
  const int cog = y >> 4;  // co base cog*64
  const int s = sidx[b];
  const int lane = t & 63, wv = t >> 6;
  const int quad = lane >> 4, l16 = lane & 15;

  // ---- one-shot burst stage: padded rows [4ne, 4ne+6) of 66x64 bf16 ----
  const unsigned short* gb = x0t + ((size_t)b * 4356 + 4 * ne * 66) * 64;
  {
    float4 v[13];
#pragma unroll
    for (int i = 0; i < 13; i++) v[i] = *(const float4*)(gb + (i * 256 + t) * 8);
#pragma unroll
    for (int i = 0; i < 13; i++) {
      int ba = (i * 256 + t) * 16;
      int sw = ba ^ (((ba >> 9) & 7) << 4);
      *(float4*)((char*)Xs + sw) = v[i];
    }
  }
  __syncthreads();

  // ---- MFMA from LDS; weights streamed (linear, L2-resident) ----
  const int co0w = cog * 64 + wv * 16;
  const unsigned short* ap = wr + ((size_t)(s * 128 + co0w + l16)) * 1024 + quad * 8;
  f32x4 acc[4];
#pragma unroll
  for (int nt = 0; nt < 4; nt++) acc[nt] = (f32x4){0.f, 0.f, 0.f, 0.f};

#pragma unroll
  for (int kc = 0; kc < 32; kc++) {
    const int tap = kc >> 1;
    const int cio = (kc & 1) * 32 + quad * 8;
    const int kh = tap >> 2, kw = tap & 3;
    bf16x8 af = *(const bf16x8*)(ap + kc * 32);
#pragma unroll
    for (int nt = 0; nt < 4; nt++) {
      int lr = 2 * (nt >> 1) + kh;               // local padded row (0..5)
      int col = 2 * ((nt & 1) * 16 + l16) + kw;  // padded col (0..65)
      int ba = ((lr * 66 + col) * 64 + cio) * 2;
      int sw = ba ^ (((ba >> 9) & 7) << 4);
      bf16x8 bv = *(const bf16x8*)((const char*)Xs + sw);
      acc[nt] = __builtin_amdgcn_mfma_f32_16x16x32_bf16(af, bv, acc[nt], 0, 0, 0);
    }
  }

#pragma unroll
  for (int nt = 0; nt < 4; nt++) {
    int p = ne * 64 + (nt >> 1) * 32 + (nt & 1) * 16 + l16;
#pragma unroll
    for (int r = 0; r < 4; r++)
      x1[((size_t)b * 128 + co0w + quad * 4 + r) * 1024 + p] = acc[nt][r];
  }
}

// ---------------------------------------------------------------------------
// in-place instance norm (+leaky), NPIX per (b,c) — proven block version
template <int NPIX>
__global__ __launch_bounds__(256) void k_inorm(float* __restrict__ x) {
  constexpr int E = NPIX / 256;
  float* p = x + (size_t)blockIdx.x * NPIX;
  const int t = threadIdx.x;
  float v[E];
  float sum = 0.f, sq = 0.f;
#pragma unroll
  for (int i = 0; i < E; i++) {
    v[i] = p[i * 256 + t];
    sum += v[i];
    sq += v[i] * v[i];
  }
#pragma unroll
  for (int o = 32; o > 0; o >>= 1) {
    sum += __shfl_down(sum, o, 64);
    sq += __shfl_down(sq, o, 64);
  }
  __shared__ float red[8];
  int wid = t >> 6;
  if ((t & 63) == 0) {
    red[wid] = sum;
    red[4 + wid] = sq;
  }
  __syncthreads();
  float S = red[0] + red[1] + red[2] + red[3];
  float SQ = red[4] + red[5] + red[6] + red[7];
  float m = S * (1.0f / NPIX);
  float var = SQ * (1.0f / NPIX) - m * m;
  float inv = rsqrtf(var + 1e-5f);
#pragma unroll
  for (int i = 0; i < E; i++) p[i * 256 + t] = LRELU((v[i] - m) * inv);
}

// ---------------------------------------------------------------------------
// fused q/k/v 1x1 projections. grid (B, 40): y<4 q, y<8 k, else v (chunked bf16)
__global__ __launch_bounds__(256) void k_proj_qkv(
    const float* __restrict__ xin, const float* __restrict__ wq,
    const float* __restrict__ bq, const float* __restrict__ wk,
    const float* __restrict__ bk, const float* __restrict__ wv,
    const float* __restrict__ bv, const int* __restrict__ sidx,
    float* __restrict__ q, float* __restrict__ kout, unsigned short* __restrict__ vpk) {
  __shared__ float xsh[32 * 256];
  __shared__ float wsh[16 * 32];
  const int t = threadIdx.x;
  const int b = blockIdx.x;
  const int y = blockIdx.y;
  const int s = sidx[b];
  const int cg = t >> 6, ng = t & 63;
  const float* w;
  const float* bias;
  int co0, nn0, CO;
  if (y < 8) {
    w = (y < 4) ? wq : wk;
    bias = (y < 4) ? bq : bk;
    co0 = 0;
    nn0 = (y & 3) * 256;
    CO = 16;
  } else {
    w = wv;
    bias = bv;
    co0 = ((y - 8) >> 2) * 16;
    nn0 = ((y - 8) & 3) * 256;
    CO = 128;
  }
  const float* xb = xin + (size_t)b * 128 * 1024;
  float4 acc4[4];
#pragma unroll
  for (int c = 0; c < 4; c++) {
    float bb = bias[s * CO + co0 + cg * 4 + c];
    acc4[c] = make_float4(bb, bb, bb, bb);
  }
  for (int cc = 0; cc < 4; cc++) {
#pragma unroll
    for (int k = 0; k < 8; k++) {
      int id = t + (k << 8);
      int ci = id >> 6, nf = id & 63;
      ((float4*)xsh)[id] = ((const float4*)(xb + (cc * 32 + ci) * 1024 + nn0))[nf];
    }
    if (t < 128)
      ((float4*)wsh)[t] =
          ((const float4*)(w + ((size_t)(s * CO + co0 + (t >> 3))) * 128 + cc * 32))[t & 7];
    __syncthreads();
#pragma unroll
    for (int ci4 = 0; ci4 < 8; ci4++) {
      float4 wvv[4], xv[4];
#pragma unroll
      for (int c = 0; c < 4; c++) wvv[c] = ((const float4*)wsh)[(cg * 4 + c) * 8 + ci4];
#pragma unroll
      for (int i = 0; i < 4; i++) xv[i] = ((const float4*)xsh)[(ci4 * 4 + i) * 64 + ng];
#pragma unroll
      for (int c = 0; c < 4; c++)
#pragma unroll
        for (int i = 0; i < 4; i++) {
          float wvc = i == 0 ? wvv[c].x : i == 1 ? wvv[c].y : i == 2 ? wvv[c].z : wvv[c].w;
          acc4[c].x += wvc * xv[i].x;
          acc4[c].y += wvc * xv[i].y;
          acc4[c].z += wvc * xv[i].z;
          acc4[c].w += wvc * xv[i].w;
        }
    }
    __syncthreads();
  }
  if (y < 8) {
    float* out = (y < 4) ? q : kout;
#pragma unroll
    for (int c = 0; c < 4; c++)
      ((float4*)(out + ((size_t)b * 16 + cg * 4 + c) * 1024 + nn0))[ng] = acc4[c];
  } else {
    int n = nn0 + ng * 4;
#pragma unroll
    for (int c = 0; c < 4; c++) {
      int co = co0 + cg * 4 + c;
      bf16x4 u;
      u[0] = f2bf(acc4[c].x);
      u[1] = f2bf(acc4[c].y);
      u[2] = f2bf(acc4[c].z);
      u[3] = f2bf(acc4[c].w);
      *(bf16x4*)(vpk + (((size_t)b * 32 + (n >> 5)) * 128 + co) * 32 + (n & 31)) = u;
    }
  }
}

// ---------------------------------------------------------------------------
// fused self-attention — round-5 proven version (SB ping-pong, (256,2))
__global__ __launch_bounds__(256, 2) void k_attn(
    const float* __restrict__ q, const float* __restrict__ k,
    const unsigned short* __restrict__ vpk, const float* __restrict__ x1,
    const float* __restrict__ gamma, const int* __restrict__ sidx,
    unsigned short* __restrict__ ybf) {
  __shared__ __align__(16) short Psh[16 * 1032];
  __shared__ float qsh[256];
  __shared__ float redm[64], reds[64];
  const int t = threadIdx.x;
  const int b = blockIdx.x >> 6;
  const int n0 = (blockIdx.x & 63) << 4;
  const int lane = t & 63, wv = t >> 6;
  const int quad = lane >> 4, l16 = lane & 15;
  const float* qb = q + (size_t)b * 16 * 1024;
  const float* kb = k + (size_t)b * 16 * 1024;
  const float* xb = x1 + (size_t)b * 128 * 1024;

  qsh[t] = qb[((t >> 4) << 10) + n0 + (t & 15)];
  __syncthreads();

  float acc[4][16];
#pragma unroll
  for (int j = 0; j < 4; j++)
#pragma unroll
    for (int nl = 0; nl < 16; nl++) acc[j][nl] = 0.0f;

  float4 KA[4], KB[4];
#define LDK(BUF, G)                                                       \
  _Pragma("unroll") for (int c4 = 0; c4 < 4; c4++)                        \
      BUF[c4] = *(const float4*)(kb + ((((G) * 4 + c4)) << 10) + 4 * t);  \
  SB;
#define MMK(BUF, G)                                                                         \
  _Pragma("unroll") for (int c4 = 0; c4 < 4; c4++) {                                        \
    const float* qr = qsh + ((G) * 4 + c4) * 16;                                            \
    _Pragma("unroll") for (int j = 0; j < 4; j++) {                                         \
      float kk = j == 0 ? BUF[c4].x : j == 1 ? BUF[c4].y : j == 2 ? BUF[c4].z : BUF[c4].w;  \
      _Pragma("unroll") for (int nl = 0; nl < 16; nl++) acc[j][nl] += kk * qr[nl];          \
    }                                                                                       \
  }                                                                                         \
  SB;

  LDK(KA, 0)
  LDK(KB, 1)
  MMK(KA, 0) LDK(KA, 2)
  MMK(KB, 1) LDK(KB, 3)
  MMK(KA, 2)
  MMK(KB, 3)
#undef LDK
#undef MMK

  float lmax[16];
#pragma unroll
  for (int nl = 0; nl < 16; nl++)
    lmax[nl] = fmaxf(fmaxf(acc[0][nl], acc[1][nl]), fmaxf(acc[2][nl], acc[3][nl]));
#pragma unroll
  for (int o = 32; o > 0; o >>= 1)
#pragma unroll
    for (int nl = 0; nl < 16; nl++) lmax[nl] = fmaxf(lmax[nl], __shfl_xor(lmax[nl], o, 64));
  if (lane == 0)
#pragma unroll
    for (int nl = 0; nl < 16; nl++) redm[wv * 16 + nl] = lmax[nl];
  __syncthreads();
#pragma unroll
  for (int nl = 0; nl < 16; nl++)
    lmax[nl] = fmaxf(fmaxf(redm[nl], redm[16 + nl]), fmaxf(redm[32 + nl], redm[48 + nl]));
  float lsum[16];
#pragma unroll
  for (int nl = 0; nl < 16; nl++) lsum[nl] = 0.0f;
#pragma unroll
  for (int j = 0; j < 4; j++)
#pragma unroll
    for (int nl = 0; nl < 16; nl++) {
      float e = __expf(acc[j][nl] - lmax[nl]);
      acc[j][nl] = e;
      lsum[nl] += e;
    }
#pragma unroll
  for (int o = 32; o > 0; o >>= 1)
#pragma unroll
    for (int nl = 0; nl < 16; nl++) lsum[nl] += __shfl_xor(lsum[nl], o, 64);
  if (lane == 0)
#pragma unroll
    for (int nl = 0; nl < 16; nl++) reds[wv * 16 + nl] = lsum[nl];
#pragma unroll
  for (int nl = 0; nl < 16; nl++) {
    bf16x4 pv;
    pv[0] = f2bf(acc[0][nl]);
    pv[1] = f2bf(acc[1][nl]);
    pv[2] = f2bf(acc[2][nl]);
    pv[3] = f2bf(acc[3][nl]);
    *(bf16x4*)&Psh[nl * 1032 + 4 * t] = pv;
  }
  __syncthreads();

  const unsigned short* vp =
      vpk + ((size_t)b * 32 * 128 + (size_t)(wv * 32 + l16)) * 32 + quad * 8;
  const short* prow = Psh + l16 * 1032 + quad * 8;
  f32x4 dacc[2];
  dacc[0] = (f32x4){0.f, 0.f, 0.f, 0.f};
  dacc[1] = (f32x4){0.f, 0.f, 0.f, 0.f};

  bf16x8 VA0[4], VA1[4], PAr[4];
  bf16x8 VB0[4], VB1[4], PBr[4];
#define LDV(V0, V1, PR, G)                                \
  _Pragma("unroll") for (int m4 = 0; m4 < 4; m4++) {      \
    int mt = (G) * 4 + m4;                                \
    V0[m4] = *(const bf16x8*)(vp + mt * 4096);            \
    V1[m4] = *(const bf16x8*)(vp + 512 + mt * 4096);      \
    PR[m4] = *(const bf16x8*)(prow + mt * 32);            \
  }                                                       \
  SB;
#define MMV(V0, V1, PR)                                                                      \
  _Pragma("unroll") for (int m4 = 0; m4 < 4; m4++) {                                         \
    dacc[0] = __builtin_amdgcn_mfma_f32_16x16x32_bf16(V0[m4], PR[m4], dacc[0], 0, 0, 0);     \
    dacc[1] = __builtin_amdgcn_mfma_f32_16x16x32_bf16(V1[m4], PR[m4], dacc[1], 0, 0, 0);     \
  }                                                                                          \
  SB;

  LDV(VA0, VA1, PAr, 0)
  LDV(VB0, VB1, PBr, 1)
  MMV(VA0, VA1, PAr) LDV(VA0, VA1, PAr, 2)
  MMV(VB0, VB1, PBr) LDV(VB0, VB1, PBr, 3)
  MMV(VA0, VA1, PAr) LDV(VA0, VA1, PAr, 4)
  MMV(VB0, VB1, PBr) LDV(VB0, VB1, PBr, 5)
  MMV(VA0, VA1, PAr) LDV(VA0, VA1, PAr, 6)
  MMV(VB0, VB1, PBr) LDV(VB0, VB1, PBr, 7)
  MMV(VA0, VA1, PAr)
  MMV(VB0, VB1, PBr)
#undef LDV
#undef MMV
  __syncthreads();

  float* Osh = (float*)Psh;
  short* Osh2 = Psh + 4352;
#pragma unroll
  for (int i = 0; i < 2; i++) {
    int cob = wv * 32 + i * 16 + quad * 4;
#pragma unroll
    for (int r = 0; r < 4; r++) Osh[(cob + r) * 17 + l16] = dacc[i][r];
  }
  __syncthreads();
  float g = gamma[sidx[b]];
  {
    int co = t >> 1, j0 = (t & 1) * 8;
    const float* xr = xb + (co << 10) + n0 + j0;
    float4 xv0 = *(const float4*)xr;
    float4 xv1 = *(const float4*)(xr + 4);
    float xs[8] = {xv0.x, xv0.y, xv0.z, xv0.w, xv1.x, xv1.y, xv1.z, xv1.w};
#pragma unroll
    for (int j = 0; j < 8; j++) {
      int nl = j0 + j;
      float rs = 1.0f / (reds[nl] + reds[16 + nl] + reds[32 + nl] + reds[48 + nl]);
      Osh2[nl * 136 + co] = f2bf(g * Osh[co * 17 + nl] * rs + xs[j]);
    }
  }
  __syncthreads();
  {
    int nl = t >> 4, cg = t & 15;
    bf16x8 u = *(const bf16x8*)&Osh2[nl * 136 + cg * 8];
    int p = n0 + nl;
    int ih = p >> 5, iw = p & 31;
    *(bf16x8*)(ybf + ((size_t)b * 1156 + (ih + 1) * 34 + (iw + 1)) * 128 + cg * 8) = u;
  }
}

// ---------------------------------------------------------------------------
// conv2: LDS-staged MFMA GEMM (proven round 8). grid (B, 32).
__global__ __launch_bounds__(256, 2) void k_conv2n(
    const unsigned short* __restrict__ ybf, const unsigned short* __restrict__ wr,
    const int* __restrict__ sidx, float* __restrict__ x2) {
  __shared__ __align__(16) unsigned short Xs[26624];  // 53,248 B (52,224 used)
  const int t = threadIdx.x;
  const int b = blockIdx.x;
  const int y = blockIdx.y;
  const int ne = y & 7;   // oh in [2ne, 2ne+2)
  const int cog = y >> 3; // co base cog*64
  const int s = sidx[b];
  const int lane = t & 63, wv = t >> 6;
  const int quad = lane >> 4, l16 = lane & 15;

  // ---- one-shot burst stage: padded rows [4ne, 4ne+6) ----
  const unsigned short* gb = ybf + ((size_t)b * 1156 + 4 * ne * 34) * 128;
  {
    float4 v[13];
#pragma unroll
    for (int i = 0; i < 13; i++) v[i] = *(const float4*)(gb + (i * 256 + t) * 8);
#pragma unroll
    for (int i = 0; i < 13; i++) {
      int ba = (i * 256 + t) * 16;
      int sw = ba ^ (((ba >> 9) & 7) << 4);
      *(float4*)((char*)Xs + sw) = v[i];
    }
  }
  __syncthreads();

  // ---- MFMA from LDS; weights streamed (linear, L2-resident) ----
  const int co0w = cog * 64 + wv * 16;
  const unsigned short* ap = wr + ((size_t)(s * 256 + co0w + l16)) * 2048 + quad * 8;
  f32x4 acc[2];
  acc[0] = (f32x4){0.f, 0.f, 0.f, 0.f};
  acc[1] = (f32x4){0.f, 0.f, 0.f, 0.f};

#pragma unroll
  for (int kc = 0; kc < 64; kc++) {
    const int tap = kc >> 2;
    const int cio = (kc & 3) * 32 + quad * 8;
    const int kh = tap >> 2, kw = tap & 3;
    bf16x8 af = *(const bf16x8*)(ap + kc * 32);
#pragma unroll
    for (int nt = 0; nt < 2; nt++) {
      int lr = 2 * nt + kh;            // local padded row (0..5)
      int col = 2 * l16 + kw;          // padded col (0..33)
      int ba = ((lr * 34 + col) * 128 + cio) * 2;
      int sw = ba ^ (((ba >> 9) & 7) << 4);
      bf16x8 bv = *(const bf16x8*)((const char*)Xs + sw);
      acc[nt] = __builtin_amdgcn_mfma_f32_16x16x32_bf16(af, bv, acc[nt], 0, 0, 0);
    }
  }

#pragma unroll
  for (int nt = 0; nt < 2; nt++) {
    int p = ne * 32 + nt * 16 + l16;
#pragma unroll
    for (int r = 0; r < 4; r++)
      x2[((size_t)b * 256 + co0w + quad * 4 + r) * 256 + p] = acc[nt][r];
  }
}

// ---------------------------------------------------------------------------
// head: x2 instance-norm (+leaky) FUSED into the head conv (x2 arrives RAW).
// Block (b,cc) stages 32 full 256-px rows -> block-local norm is exact.
__global__ __launch_bounds__(256) void k_head_part(
    const float* __restrict__ x2, const float* __restrict__ wh,
    const int* __restrict__ sidx, float* __restrict__ out) {
  __shared__ float Xs[32 * 256];
  __shared__ float Wsh[512];
  __shared__ float sm[32], si[32];
  const int t = threadIdx.x;
  const int b = blockIdx.x, cc = blockIdx.y;
  const int s = sidx[b];
  const float* xp = x2 + ((size_t)b * 256 + cc * 32) * 256;
#pragma unroll
  for (int i = 0; i < 32; i++) Xs[i * 256 + t] = xp[i * 256 + t];
#pragma unroll
  for (int i = 0; i < 2; i++) {
    int idx = i * 256 + t;
    Wsh[idx] = wh[s * 4096 + cc * 512 + idx];
  }
  __syncthreads();
  // per-row mean/var: 8 lanes per row (rows stay inside one wave's 8-lane grp)
  {
    int r = t >> 3, c0 = (t & 7) * 32;
    float sv = 0.f, sq = 0.f;
#pragma unroll
    for (int j = 0; j < 32; j++) {
      float v = Xs[r * 256 + c0 + j];
      sv += v;
      sq += v * v;
    }
#pragma unroll
    for (int o = 1; o < 8; o <<= 1) {
      sv += __shfl_xor(sv, o, 64);
      sq += __shfl_xor(sq, o, 64);
    }
    if ((t & 7) == 0) {
      float m = sv * (1.0f / 256.0f);
      float var = sq * (1.0f / 256.0f) - m * m;
      sm[r] = m;
      si[r] = rsqrtf(var + 1e-5f);
    }
  }
  __syncthreads();
#pragma unroll
  for (int i = 0; i < 32; i++) {
    float v = (Xs[i * 256 + t] - sm[i]) * si[i];
    Xs[i * 256 + t] = LRELU(v);
  }
  __syncthreads();
  if (t < 225) {
    int oh = t / 15, ow = t % 15;
    float acc = 0.0f;
    for (int ci = 0; ci < 32; ci++) {
      const float* xr = Xs + ci * 256;
      const float* wr = Wsh + ci * 16;
#pragma unroll
      for (int kh = 0; kh < 4; kh++) {
        int ih = oh - 1 + kh;
        if ((unsigned)ih >= 16u) continue;
#pragma unroll
        for (int kw = 0; kw < 4; kw++) {
          int iw = ow - 1 + kw;
          if ((unsigned)iw >= 16u) continue;
          acc += wr[kh * 4 + kw] * xr[(ih << 4) + iw];
        }
      }
    }
    atomicAdd(out + b * 225 + t, acc);
  }
}

// ---------------------------------------------------------------------------
extern "C" void kernel_launch(void* const* d_in, const int* in_sizes, int n_in,
                              void* d_out, int out_size, void* d_ws, size_t ws_size,
                              hipStream_t stream) {
  const float* img = (const float*)d_in[0];
  const int* sidx = (const int*)d_in[1];
  const float* w0 = (const float*)d_in[2];
  const float* b0 = (const float*)d_in[3];
  const float* w1 = (const float*)d_in[4];
  const float* w2 = (const float*)d_in[6];
  const float* wq = (const float*)d_in[8];
  const float* bq = (const float*)d_in[9];
  const float* wk = (const float*)d_in[10];
  const float* bk = (const float*)d_in[11];
  const float* wv = (const float*)d_in[12];
  const float* bv = (const float*)d_in[13];
  const float* gamma = (const float*)d_in[14];
  const float* wh = (const float*)d_in[15];
  const float* bh = (const float*)d_in[16];
  float* out = (float*)d_out;

  float* ws = (float*)d_ws;
  unsigned short* x0t = (unsigned short*)(ws);            // padded 66x66: 16*4356*64 shorts
  float* x1 = ws + 2359296;                               // [2.25M,4.25M)
  float* q = ws + 4456448;                                // [4.25M,4.5M)
  float* k = ws + 4718592;                                // [4.5M,4.75M)
  unsigned short* vpk = (unsigned short*)(ws + 4980736);  // [4.75M,5.75M)
  unsigned short* ybf = (unsigned short*)(ws + 6029312);  // padded 34x34: 16*1156*128 shorts
  float* x2 = ws + 7340032;                               // [7M,8M)
  unsigned short* wr1 = (unsigned short*)(ws + 8912896);  // [8.5M,8.75M)
  unsigned short* wr2 = (unsigned short*)(ws + 9175040);  // [8.75M,9.75M)

  const int B = 16;

  // prologue: vec4 repack + bias-out + borders (blocks 0..2836) + conv0 (4096)
  k_repack_all<<<6933, 256, 0, stream>>>(w1, wr1, w2, wr2, bh, sidx, out, x0t, ybf,
                                         img, w0, b0);
  k_conv1n<<<dim3(B, 32), 256, 0, stream>>>(x0t, wr1, sidx, x1);
  k_inorm<1024><<<B * 128, 256, 0, stream>>>(x1);
  k_proj_qkv<<<dim3(B, 40), 256, 0, stream>>>(x1, wq, bq, wk, bk, wv, bv, sidx, q, k, vpk);
  k_attn<<<B * 64, 256, 0, stream>>>(q, k, vpk, x1, gamma, sidx, ybf);
  k_conv2n<<<dim3(B, 32), 256, 0, stream>>>(ybf, wr2, sidx, x2);
  k_head_part<<<dim3(B, 8), 256, 0, stream>>>(x2, wh, sidx, out);
}

// Round 11
// 197.642 us; speedup vs baseline: 1.3771x; 1.0172x over previous
//
#include <hip/hip_runtime.h>

#define LRELU(x) ((x) > 0.0f ? (x) : 0.2f * (x))
#define SB __builtin_amdgcn_sched_barrier(0)

typedef short bf16x8 __attribute__((ext_vector_type(8)));
typedef short bf16x4 __attribute__((ext_vector_type(4)));
typedef float f32x4 __attribute__((ext_vector_type(4)));

__device__ __forceinline__ short f2bf(float f) {
  union { float f; unsigned u; } x{f};
  return (short)((x.u + 0x7FFF + ((x.u >> 16) & 1)) >> 16);
}

// ---------------------------------------------------------------------------
// fused prologue: weight repack (float4-vectorized coalesced reads) +
// head-bias out init + border zeroing + x1-stat zeroing + conv0 (>= 2853).
// thread segments: [0,131072) w1-vec4 | [..,655360) w2-vec4 |
// [..,658960) bias | [..,692240) x0t border | [..,726032) ybf border |
// [..,730128) stat zero
__global__ __launch_bounds__(256) void k_repack_all(
    const float* __restrict__ w1, unsigned short* __restrict__ wr1,
    const float* __restrict__ w2, unsigned short* __restrict__ wr2,
    const float* __restrict__ bh, const int* __restrict__ sidx,
    float* __restrict__ out, unsigned short* __restrict__ x0t,
    unsigned short* __restrict__ ybf, const float* __restrict__ img,
    const float* __restrict__ w0, const float* __restrict__ b0,
    float* __restrict__ stat) {
  __shared__ float Ish[4 * 34];
  if (blockIdx.x >= 2853) {
    // ---- conv0 segment: img (B,1,128,128) -> x0t padded 66x66 NHWC bf16
    const int t = threadIdx.x;
    const int q = blockIdx.x - 2853;
    const int b = q >> 8, py = q & 255;
    const int oh = py >> 2, owb = (py & 3) << 4;
    const int s = sidx[b];
    const float* ip = img + (size_t)b * 16384;
    if (t < 136) {
      int r = t / 34, c = t % 34;
      int ih = 2 * oh - 1 + r, iw = 2 * owb - 1 + c;
      Ish[t] = ((unsigned)ih < 128u && (unsigned)iw < 128u) ? ip[ih * 128 + iw] : 0.f;
    }
    const int co = t & 63, ps = t >> 6;
    float wreg[16];
    const float* wp = w0 + (s * 64 + co) * 16;
#pragma unroll
    for (int i = 0; i < 16; i++) wreg[i] = wp[i];
    float bb = b0[s * 64 + co];
    __syncthreads();
    unsigned short* op = x0t + ((size_t)b * 4356 + (oh + 1) * 66 + (owb + 1)) * 64 + co;
#pragma unroll
    for (int j = 0; j < 4; j++) {
      int pl = ps * 4 + j;
      float acc = bb;
#pragma unroll
      for (int kh = 0; kh < 4; kh++)
#pragma unroll
        for (int kw = 0; kw < 4; kw++)
          acc += wreg[kh * 4 + kw] * Ish[kh * 34 + pl * 2 + kw];
      acc = LRELU(acc);
      op[pl * 64] = (unsigned short)f2bf(acc);
    }
    return;
  }
  int idx = blockIdx.x * 256 + threadIdx.x;
  if (idx < 131072) {
    // w1 vec4: 4 consecutive taps, same (ci,sco)
    float4 v = *(const float4*)(w1 + (size_t)idx * 4);
    int base = idx * 4;
    int tap0 = base & 15;
    int rest = base >> 4;
    int ci = rest & 63, sco = rest >> 6;
    unsigned short* d = wr1 + (size_t)sco * 1024 + ci;
    d[(tap0 + 0) * 64] = (unsigned short)f2bf(v.x);
    d[(tap0 + 1) * 64] = (unsigned short)f2bf(v.y);
    d[(tap0 + 2) * 64] = (unsigned short)f2bf(v.z);
    d[(tap0 + 3) * 64] = (unsigned short)f2bf(v.w);
    return;
  } else if (idx < 655360) {
    // w2 vec4
    int i = idx - 131072;
    float4 v = *(const float4*)(w2 + (size_t)i * 4);
    int base = i * 4;
    int tap0 = base & 15;
    int rest = base >> 4;
    int ci = rest & 127, sco = rest >> 7;
    unsigned short* d = wr2 + (size_t)sco * 2048 + ci;
    d[(tap0 + 0) * 128] = (unsigned short)f2bf(v.x);
    d[(tap0 + 1) * 128] = (unsigned short)f2bf(v.y);
    d[(tap0 + 2) * 128] = (unsigned short)f2bf(v.z);
    d[(tap0 + 3) * 128] = (unsigned short)f2bf(v.w);
    return;
  } else if (idx < 658960) {
    int i = idx - 655360;
    if (i < 3600) out[i] = bh[sidx[i / 225]];
    return;
  } else if (idx < 692240) {
    // zero x0t border
    int i = idx - 658960;
    int b = i / 2080, r = i % 2080;
    int pix = r >> 3, sub = r & 7;
    int row, col;
    if (pix < 66) { row = 0; col = pix; }
    else if (pix < 132) { row = 65; col = pix - 66; }
    else { int qq = pix - 132; row = 1 + (qq >> 1); col = (qq & 1) * 65; }
    bf16x8 z = {0, 0, 0, 0, 0, 0, 0, 0};
    *(bf16x8*)(x0t + ((size_t)b * 4356 + row * 66 + col) * 64 + sub * 8) = z;
    return;
  } else if (idx < 726032) {
    // zero ybf border
    int i = idx - 692240;
    if (i >= 33792) return;
    int b = i / 2112, r = i % 2112;
    int pix = r >> 4, sub = r & 15;
    int row, col;
    if (pix < 34) { row = 0; col = pix; }
    else if (pix < 68) { row = 33; col = pix - 34; }
    else { int qq = pix - 68; row = 1 + (qq >> 1); col = (qq & 1) * 33; }
    bf16x8 z = {0, 0, 0, 0, 0, 0, 0, 0};
    *(bf16x8*)(ybf + ((size_t)b * 1156 + row * 34 + col) * 128 + sub * 8) = z;
    return;
  } else {
    // zero x1 stats (16 b x 128 co x 2)
    int i = idx - 726032;
    if (i < 4096) stat[i] = 0.f;
    return;
  }
}

// ---------------------------------------------------------------------------
// conv1: LDS-staged MFMA GEMM (proven round 9) + x1 norm-stat accumulation:
// each wave reduces (sum, sum^2) of its 64 px per co, atomicAdds per-co stats.
// x1 is stored RAW; consumers apply LRELU((v-m)*inv) lazily.
__global__ __launch_bounds__(256, 2) void k_conv1n(
    const unsigned short* __restrict__ x0t, const unsigned short* __restrict__ wr,
    const int* __restrict__ sidx, float* __restrict__ x1,
    float* __restrict__ stat) {
  __shared__ __align__(16) unsigned short Xs[26624];  // 53,248 B (50,688 used)
  const int t = threadIdx.x;
  const int b = blockIdx.x;
  const int y = blockIdx.y;
  const int ne = y & 15;   // output rows [2ne, 2ne+2)
  const int cog = y >> 4;  // co base cog*64
  const int s = sidx[b];
  const int lane = t & 63, wv = t >> 6;
  const int quad = lane >> 4, l16 = lane & 15;

  // ---- one-shot burst stage: padded rows [4ne, 4ne+6) of 66x64 bf16 ----
  const unsigned short* gb = x0t + ((size_t)b * 4356 + 4 * ne * 66) * 64;
  {
    float4 v[13];
#pragma unroll
    for (int i = 0; i < 13; i++) v[i] = *(const float4*)(gb + (i * 256 + t) * 8);
#pragma unroll
    for (int i = 0; i < 13; i++) {
      int ba = (i * 256 + t) * 16;
      int sw = ba ^ (((ba >> 9) & 7) << 4);
      *(float4*)((char*)Xs + sw) = v[i];
    }
  }
  __syncthreads();

  // ---- MFMA from LDS; weights streamed (linear, L2-resident) ----
  const int co0w = cog * 64 + wv * 16;
  const unsigned short* ap = wr + ((size_t)(s * 128 + co0w + l16)) * 1024 + quad * 8;
  f32x4 acc[4];
#pragma unroll
  for (int nt = 0; nt < 4; nt++) acc[nt] = (f32x4){0.f, 0.f, 0.f, 0.f};

#pragma unroll
  for (int kc = 0; kc < 32; kc++) {
    const int tap = kc >> 1;
    const int cio = (kc & 1) * 32 + quad * 8;
    const int kh = tap >> 2, kw = tap & 3;
    bf16x8 af = *(const bf16x8*)(ap + kc * 32);
#pragma unroll
    for (int nt = 0; nt < 4; nt++) {
      int lr = 2 * (nt >> 1) + kh;               // local padded row (0..5)
      int col = 2 * ((nt & 1) * 16 + l16) + kw;  // padded col (0..65)
      int ba = ((lr * 66 + col) * 64 + cio) * 2;
      int sw = ba ^ (((ba >> 9) & 7) << 4);
      bf16x8 bv = *(const bf16x8*)((const char*)Xs + sw);
      acc[nt] = __builtin_amdgcn_mfma_f32_16x16x32_bf16(af, bv, acc[nt], 0, 0, 0);
    }
  }

  // ---- per-co (sum, sum^2) over this wave's 64 px; atomic merge ----
#pragma unroll
  for (int r = 0; r < 4; r++) {
    float sv = acc[0][r] + acc[1][r] + acc[2][r] + acc[3][r];
    float sq = acc[0][r] * acc[0][r] + acc[1][r] * acc[1][r] +
               acc[2][r] * acc[2][r] + acc[3][r] * acc[3][r];
#pragma unroll
    for (int o = 1; o < 16; o <<= 1) {
      sv += __shfl_xor(sv, o, 64);
      sq += __shfl_xor(sq, o, 64);
    }
    if (l16 == 0) {
      int co = co0w + quad * 4 + r;
      atomicAdd(&stat[(b * 128 + co) * 2 + 0], sv);
      atomicAdd(&stat[(b * 128 + co) * 2 + 1], sq);
    }
  }

#pragma unroll
  for (int nt = 0; nt < 4; nt++) {
    int p = ne * 64 + (nt >> 1) * 32 + (nt & 1) * 16 + l16;
#pragma unroll
    for (int r = 0; r < 4; r++)
      x1[((size_t)b * 128 + co0w + quad * 4 + r) * 1024 + p] = acc[nt][r];
  }
}

// ---------------------------------------------------------------------------
// fused q/k/v 1x1 projections over RAW x1; per-ci norm+lrelu applied while
// staging, using conv1n's stats. grid (B, 40).
__global__ __launch_bounds__(256) void k_proj_qkv(
    const float* __restrict__ xin, const float* __restrict__ wq,
    const float* __restrict__ bq, const float* __restrict__ wk,
    const float* __restrict__ bk, const float* __restrict__ wv,
    const float* __restrict__ bv, const int* __restrict__ sidx,
    const float* __restrict__ stat,
    float* __restrict__ q, float* __restrict__ kout, unsigned short* __restrict__ vpk) {
  __shared__ float xsh[32 * 256];
  __shared__ float wsh[16 * 32];
  __shared__ float msh[128], ish[128];
  const int t = threadIdx.x;
  const int b = blockIdx.x;
  const int y = blockIdx.y;
  const int s = sidx[b];
  const int cg = t >> 6, ng = t & 63;
  const float* w;
  const float* bias;
  int co0, nn0, CO;
  if (y < 8) {
    w = (y < 4) ? wq : wk;
    bias = (y < 4) ? bq : bk;
    co0 = 0;
    nn0 = (y & 3) * 256;
    CO = 16;
  } else {
    w = wv;
    bias = bv;
    co0 = ((y - 8) >> 2) * 16;
    nn0 = ((y - 8) & 3) * 256;
    CO = 128;
  }
  if (t < 128) {
    float sv = stat[(b * 128 + t) * 2 + 0];
    float sq = stat[(b * 128 + t) * 2 + 1];
    float m = sv * (1.0f / 1024.0f);
    float var = sq * (1.0f / 1024.0f) - m * m;
    msh[t] = m;
    ish[t] = rsqrtf(var + 1e-5f);
  }
  const float* xb = xin + (size_t)b * 128 * 1024;
  float4 acc4[4];
#pragma unroll
  for (int c = 0; c < 4; c++) {
    float bb = bias[s * CO + co0 + cg * 4 + c];
    acc4[c] = make_float4(bb, bb, bb, bb);
  }
  __syncthreads();
  for (int cc = 0; cc < 4; cc++) {
#pragma unroll
    for (int k = 0; k < 8; k++) {
      int id = t + (k << 8);
      int ci = id >> 6, nf = id & 63;
      float4 v = ((const float4*)(xb + (cc * 32 + ci) * 1024 + nn0))[nf];
      float m = msh[cc * 32 + ci], iv = ish[cc * 32 + ci];
      v.x = (v.x - m) * iv; v.x = LRELU(v.x);
      v.y = (v.y - m) * iv; v.y = LRELU(v.y);
      v.z = (v.z - m) * iv; v.z = LRELU(v.z);
      v.w = (v.w - m) * iv; v.w = LRELU(v.w);
      ((float4*)xsh)[id] = v;
    }
    if (t < 128)
      ((float4*)wsh)[t] =
          ((const float4*)(w + ((size_t)(s * CO + co0 + (t >> 3))) * 128 + cc * 32))[t & 7];
    __syncthreads();
#pragma unroll
    for (int ci4 = 0; ci4 < 8; ci4++) {
      float4 wvv[4], xv[4];
#pragma unroll
      for (int c = 0; c < 4; c++) wvv[c] = ((const float4*)wsh)[(cg * 4 + c) * 8 + ci4];
#pragma unroll
      for (int i = 0; i < 4; i++) xv[i] = ((const float4*)xsh)[(ci4 * 4 + i) * 64 + ng];
#pragma unroll
      for (int c = 0; c < 4; c++)
#pragma unroll
        for (int i = 0; i < 4; i++) {
          float wvc = i == 0 ? wvv[c].x : i == 1 ? wvv[c].y : i == 2 ? wvv[c].z : wvv[c].w;
          acc4[c].x += wvc * xv[i].x;
          acc4[c].y += wvc * xv[i].y;
          acc4[c].z += wvc * xv[i].z;
          acc4[c].w += wvc * xv[i].w;
        }
    }
    __syncthreads();
  }
  if (y < 8) {
    float* out = (y < 4) ? q : kout;
#pragma unroll
    for (int c = 0; c < 4; c++)
      ((float4*)(out + ((size_t)b * 16 + cg * 4 + c) * 1024 + nn0))[ng] = acc4[c];
  } else {
    int n = nn0 + ng * 4;
#pragma unroll
    for (int c = 0; c < 4; c++) {
      int co = co0 + cg * 4 + c;
      bf16x4 u;
      u[0] = f2bf(acc4[c].x);
      u[1] = f2bf(acc4[c].y);
      u[2] = f2bf(acc4[c].z);
      u[3] = f2bf(acc4[c].w);
      *(bf16x4*)(vpk + (((size_t)b * 32 + (n >> 5)) * 128 + co) * 32 + (n & 31)) = u;
    }
  }
}

// ---------------------------------------------------------------------------
// fused self-attention — round-5 proven version; residual read applies the
// lazy x1 normalization from stats.
__global__ __launch_bounds__(256, 2) void k_attn(
    const float* __restrict__ q, const float* __restrict__ k,
    const unsigned short* __restrict__ vpk, const float* __restrict__ x1,
    const float* __restrict__ gamma, const int* __restrict__ sidx,
    const float* __restrict__ stat, unsigned short* __restrict__ ybf) {
  __shared__ __align__(16) short Psh[16 * 1032];
  __shared__ float qsh[256];
  __shared__ float redm[64], reds[64];
  const int t = threadIdx.x;
  const int b = blockIdx.x >> 6;
  const int n0 = (blockIdx.x & 63) << 4;
  const int lane = t & 63, wv = t >> 6;
  const int quad = lane >> 4, l16 = lane & 15;
  const float* qb = q + (size_t)b * 16 * 1024;
  const float* kb = k + (size_t)b * 16 * 1024;
  const float* xb = x1 + (size_t)b * 128 * 1024;

  qsh[t] = qb[((t >> 4) << 10) + n0 + (t & 15)];
  __syncthreads();

  float acc[4][16];
#pragma unroll
  for (int j = 0; j < 4; j++)
#pragma unroll
    for (int nl = 0; nl < 16; nl++) acc[j][nl] = 0.0f;

  float4 KA[4], KB[4];
#define LDK(BUF, G)                                                       \
  _Pragma("unroll") for (int c4 = 0; c4 < 4; c4++)                        \
      BUF[c4] = *(const float4*)(kb + ((((G) * 4 + c4)) << 10) + 4 * t);  \
  SB;
#define MMK(BUF, G)                                                                         \
  _Pragma("unroll") for (int c4 = 0; c4 < 4; c4++) {                                        \
    const float* qr = qsh + ((G) * 4 + c4) * 16;                                            \
    _Pragma("unroll") for (int j = 0; j < 4; j++) {                                         \
      float kk = j == 0 ? BUF[c4].x : j == 1 ? BUF[c4].y : j == 2 ? BUF[c4].z : BUF[c4].w;  \
      _Pragma("unroll") for (int nl = 0; nl < 16; nl++) acc[j][nl] += kk * qr[nl];          \
    }                                                                                       \
  }                                                                                         \
  SB;

  LDK(KA, 0)
  LDK(KB, 1)
  MMK(KA, 0) LDK(KA, 2)
  MMK(KB, 1) LDK(KB, 3)
  MMK(KA, 2)
  MMK(KB, 3)
#undef LDK
#undef MMK

  float lmax[16];
#pragma unroll
  for (int nl = 0; nl < 16; nl++)
    lmax[nl] = fmaxf(fmaxf(acc[0][nl], acc[1][nl]), fmaxf(acc[2][nl], acc[3][nl]));
#pragma unroll
  for (int o = 32; o > 0; o >>= 1)
#pragma unroll
    for (int nl = 0; nl < 16; nl++) lmax[nl] = fmaxf(lmax[nl], __shfl_xor(lmax[nl], o, 64));
  if (lane == 0)
#pragma unroll
    for (int nl = 0; nl < 16; nl++) redm[wv * 16 + nl] = lmax[nl];
  __syncthreads();
#pragma unroll
  for (int nl = 0; nl < 16; nl++)
    lmax[nl] = fmaxf(fmaxf(redm[nl], redm[16 + nl]), fmaxf(redm[32 + nl], redm[48 + nl]));
  float lsum[16];
#pragma unroll
  for (int nl = 0; nl < 16; nl++) lsum[nl] = 0.0f;
#pragma unroll
  for (int j = 0; j < 4; j++)
#pragma unroll
    for (int nl = 0; nl < 16; nl++) {
      float e = __expf(acc[j][nl] - lmax[nl]);
      acc[j][nl] = e;
      lsum[nl] += e;
    }
#pragma unroll
  for (int o = 32; o > 0; o >>= 1)
#pragma unroll
    for (int nl = 0; nl < 16; nl++) lsum[nl] += __shfl_xor(lsum[nl], o, 64);
  if (lane == 0)
#pragma unroll
    for (int nl = 0; nl < 16; nl++) reds[wv * 16 + nl] = lsum[nl];
#pragma unroll
  for (int nl = 0; nl < 16; nl++) {
    bf16x4 pv;
    pv[0] = f2bf(acc[0][nl]);
    pv[1] = f2bf(acc[1][nl]);
    pv[2] = f2bf(acc[2][nl]);
    pv[3] = f2bf(acc[3][nl]);
    *(bf16x4*)&Psh[nl * 1032 + 4 * t] = pv;
  }
  __syncthreads();

  const unsigned short* vp =
      vpk + ((size_t)b * 32 * 128 + (size_t)(wv * 32 + l16)) * 32 + quad * 8;
  const short* prow = Psh + l16 * 1032 + quad * 8;
  f32x4 dacc[2];
  dacc[0] = (f32x4){0.f, 0.f, 0.f, 0.f};
  dacc[1] = (f32x4){0.f, 0.f, 0.f, 0.f};

  bf16x8 VA0[4], VA1[4], PAr[4];
  bf16x8 VB0[4], VB1[4], PBr[4];
#define LDV(V0, V1, PR, G)                                \
  _Pragma("unroll") for (int m4 = 0; m4 < 4; m4++) {      \
    int mt = (G) * 4 + m4;                                \
    V0[m4] = *(const bf16x8*)(vp + mt * 4096);            \
    V1[m4] = *(const bf16x8*)(vp + 512 + mt * 4096);      \
    PR[m4] = *(const bf16x8*)(prow + mt * 32);            \
  }                                                       \
  SB;
#define MMV(V0, V1, PR)                                                                      \
  _Pragma("unroll") for (int m4 = 0; m4 < 4; m4++) {                                         \
    dacc[0] = __builtin_amdgcn_mfma_f32_16x16x32_bf16(V0[m4], PR[m4], dacc[0], 0, 0, 0);     \
    dacc[1] = __builtin_amdgcn_mfma_f32_16x16x32_bf16(V1[m4], PR[m4], dacc[1], 0, 0, 0);     \
  }                                                                                          \
  SB;

  LDV(VA0, VA1, PAr, 0)
  LDV(VB0, VB1, PBr, 1)
  MMV(VA0, VA1, PAr) LDV(VA0, VA1, PAr, 2)
  MMV(VB0, VB1, PBr) LDV(VB0, VB1, PBr, 3)
  MMV(VA0, VA1, PAr) LDV(VA0, VA1, PAr, 4)
  MMV(VB0, VB1, PBr) LDV(VB0, VB1, PBr, 5)
  MMV(VA0, VA1, PAr) LDV(VA0, VA1, PAr, 6)
  MMV(VB0, VB1, PBr) LDV(VB0, VB1, PBr, 7)
  MMV(VA0, VA1, PAr)
  MMV(VB0, VB1, PBr)
#undef LDV
#undef MMV
  __syncthreads();

  float* Osh = (float*)Psh;
  short* Osh2 = Psh + 4352;
#pragma unroll
  for (int i = 0; i < 2; i++) {
    int cob = wv * 32 + i * 16 + quad * 4;
#pragma unroll
    for (int r = 0; r < 4; r++) Osh[(cob + r) * 17 + l16] = dacc[i][r];
  }
  __syncthreads();
  float g = gamma[sidx[b]];
  {
    int co = t >> 1, j0 = (t & 1) * 8;
    float sv = stat[(b * 128 + co) * 2 + 0];
    float sq = stat[(b * 128 + co) * 2 + 1];
    float mm = sv * (1.0f / 1024.0f);
    float iv = rsqrtf(sq * (1.0f / 1024.0f) - mm * mm + 1e-5f);
    const float* xr = xb + (co << 10) + n0 + j0;
    float4 xv0 = *(const float4*)xr;
    float4 xv1 = *(const float4*)(xr + 4);
    float xs[8] = {xv0.x, xv0.y, xv0.z, xv0.w, xv1.x, xv1.y, xv1.z, xv1.w};
#pragma unroll
    for (int j = 0; j < 8; j++) {
      float nv = (xs[j] - mm) * iv;
      xs[j] = LRELU(nv);
    }
#pragma unroll
    for (int j = 0; j < 8; j++) {
      int nl = j0 + j;
      float rs = 1.0f / (reds[nl] + reds[16 + nl] + reds[32 + nl] + reds[48 + nl]);
      Osh2[nl * 136 + co] = f2bf(g * Osh[co * 17 + nl] * rs + xs[j]);
    }
  }
  __syncthreads();
  {
    int nl = t >> 4, cg = t & 15;
    bf16x8 u = *(const bf16x8*)&Osh2[nl * 136 + cg * 8];
    int p = n0 + nl;
    int ih = p >> 5, iw = p & 31;
    *(bf16x8*)(ybf + ((size_t)b * 1156 + (ih + 1) * 34 + (iw + 1)) * 128 + cg * 8) = u;
  }
}

// ---------------------------------------------------------------------------
// conv2: LDS-staged MFMA GEMM (proven round 8). grid (B, 32).
__global__ __launch_bounds__(256, 2) void k_conv2n(
    const unsigned short* __restrict__ ybf, const unsigned short* __restrict__ wr,
    const int* __restrict__ sidx, float* __restrict__ x2) {
  __shared__ __align__(16) unsigned short Xs[26624];  // 53,248 B (52,224 used)
  const int t = threadIdx.x;
  const int b = blockIdx.x;
  const int y = blockIdx.y;
  const int ne = y & 7;   // oh in [2ne, 2ne+2)
  const int cog = y >> 3; // co base cog*64
  const int s = sidx[b];
  const int lane = t & 63, wv = t >> 6;
  const int quad = lane >> 4, l16 = lane & 15;

  // ---- one-shot burst stage: padded rows [4ne, 4ne+6) ----
  const unsigned short* gb = ybf + ((size_t)b * 1156 + 4 * ne * 34) * 128;
  {
    float4 v[13];
#pragma unroll
    for (int i = 0; i < 13; i++) v[i] = *(const float4*)(gb + (i * 256 + t) * 8);
#pragma unroll
    for (int i = 0; i < 13; i++) {
      int ba = (i * 256 + t) * 16;
      int sw = ba ^ (((ba >> 9) & 7) << 4);
      *(float4*)((char*)Xs + sw) = v[i];
    }
  }
  __syncthreads();

  // ---- MFMA from LDS; weights streamed (linear, L2-resident) ----
  const int co0w = cog * 64 + wv * 16;
  const unsigned short* ap = wr + ((size_t)(s * 256 + co0w + l16)) * 2048 + quad * 8;
  f32x4 acc[2];
  acc[0] = (f32x4){0.f, 0.f, 0.f, 0.f};
  acc[1] = (f32x4){0.f, 0.f, 0.f, 0.f};

#pragma unroll
  for (int kc = 0; kc < 64; kc++) {
    const int tap = kc >> 2;
    const int cio = (kc & 3) * 32 + quad * 8;
    const int kh = tap >> 2, kw = tap & 3;
    bf16x8 af = *(const bf16x8*)(ap + kc * 32);
#pragma unroll
    for (int nt = 0; nt < 2; nt++) {
      int lr = 2 * nt + kh;            // local padded row (0..5)
      int col = 2 * l16 + kw;          // padded col (0..33)
      int ba = ((lr * 34 + col) * 128 + cio) * 2;
      int sw = ba ^ (((ba >> 9) & 7) << 4);
      bf16x8 bv = *(const bf16x8*)((const char*)Xs + sw);
      acc[nt] = __builtin_amdgcn_mfma_f32_16x16x32_bf16(af, bv, acc[nt], 0, 0, 0);
    }
  }

#pragma unroll
  for (int nt = 0; nt < 2; nt++) {
    int p = ne * 32 + nt * 16 + l16;
#pragma unroll
    for (int r = 0; r < 4; r++)
      x2[((size_t)b * 256 + co0w + quad * 4 + r) * 256 + p] = acc[nt][r];
  }
}

// ---------------------------------------------------------------------------
// head: x2 instance-norm (+leaky) FUSED into the head conv (x2 arrives RAW).
__global__ __launch_bounds__(256) void k_head_part(
    const float* __restrict__ x2, const float* __restrict__ wh,
    const int* __restrict__ sidx, float* __restrict__ out) {
  __shared__ float Xs[32 * 256];
  __shared__ float Wsh[512];
  __shared__ float sm[32], si[32];
  const int t = threadIdx.x;
  const int b = blockIdx.x, cc = blockIdx.y;
  const int s = sidx[b];
  const float* xp = x2 + ((size_t)b * 256 + cc * 32) * 256;
#pragma unroll
  for (int i = 0; i < 32; i++) Xs[i * 256 + t] = xp[i * 256 + t];
#pragma unroll
  for (int i = 0; i < 2; i++) {
    int idx = i * 256 + t;
    Wsh[idx] = wh[s * 4096 + cc * 512 + idx];
  }
  __syncthreads();
  {
    int r = t >> 3, c0 = (t & 7) * 32;
    float sv = 0.f, sq = 0.f;
#pragma unroll
    for (int j = 0; j < 32; j++) {
      float v = Xs[r * 256 + c0 + j];
      sv += v;
      sq += v * v;
    }
#pragma unroll
    for (int o = 1; o < 8; o <<= 1) {
      sv += __shfl_xor(sv, o, 64);
      sq += __shfl_xor(sq, o, 64);
    }
    if ((t & 7) == 0) {
      float m = sv * (1.0f / 256.0f);
      float var = sq * (1.0f / 256.0f) - m * m;
      sm[r] = m;
      si[r] = rsqrtf(var + 1e-5f);
    }
  }
  __syncthreads();
#pragma unroll
  for (int i = 0; i < 32; i++) {
    float v = (Xs[i * 256 + t] - sm[i]) * si[i];
    Xs[i * 256 + t] = LRELU(v);
  }
  __syncthreads();
  if (t < 225) {
    int oh = t / 15, ow = t % 15;
    float acc = 0.0f;
    for (int ci = 0; ci < 32; ci++) {
      const float* xr = Xs + ci * 256;
      const float* wr = Wsh + ci * 16;
#pragma unroll
      for (int kh = 0; kh < 4; kh++) {
        int ih = oh - 1 + kh;
        if ((unsigned)ih >= 16u) continue;
#pragma unroll
        for (int kw = 0; kw < 4; kw++) {
          int iw = ow - 1 + kw;
          if ((unsigned)iw >= 16u) continue;
          acc += wr[kh * 4 + kw] * xr[(ih << 4) + iw];
        }
      }
    }
    atomicAdd(out + b * 225 + t, acc);
  }
}

// ---------------------------------------------------------------------------
extern "C" void kernel_launch(void* const* d_in, const int* in_sizes, int n_in,
                              void* d_out, int out_size, void* d_ws, size_t ws_size,
                              hipStream_t stream) {
  const float* img = (const float*)d_in[0];
  const int* sidx = (const int*)d_in[1];
  const float* w0 = (const float*)d_in[2];
  const float* b0 = (const float*)d_in[3];
  const float* w1 = (const float*)d_in[4];
  const float* w2 = (const float*)d_in[6];
  const float* wq = (const float*)d_in[8];
  const float* bq = (const float*)d_in[9];
  const float* wk = (const float*)d_in[10];
  const float* bk = (const float*)d_in[11];
  const float* wv = (const float*)d_in[12];
  const float* bv = (const float*)d_in[13];
  const float* gamma = (const float*)d_in[14];
  const float* wh = (const float*)d_in[15];
  const float* bh = (const float*)d_in[16];
  float* out = (float*)d_out;

  float* ws = (float*)d_ws;
  unsigned short* x0t = (unsigned short*)(ws);            // padded 66x66: 16*4356*64 shorts
  float* x1 = ws + 2359296;                               // [2.25M,4.25M)
  float* q = ws + 4456448;                                // [4.25M,4.5M)
  float* k = ws + 4718592;                                // [4.5M,4.75M)
  unsigned short* vpk = (unsigned short*)(ws + 4980736);  // [4.75M,5.75M)
  unsigned short* ybf = (unsigned short*)(ws + 6029312);  // padded 34x34: 16*1156*128 shorts
  float* x2 = ws + 7340032;                               // [7M,8M)
  float* stat = ws + 8650752;                             // [8.25M,+4096) x1 norm stats
  unsigned short* wr1 = (unsigned short*)(ws + 8912896);  // [8.5M,8.75M)
  unsigned short* wr2 = (unsigned short*)(ws + 9175040);  // [8.75M,9.75M)

  const int B = 16;

  // prologue: vec4 repack + bias-out + borders + stat zero (0..2852) + conv0
  k_repack_all<<<6949, 256, 0, stream>>>(w1, wr1, w2, wr2, bh, sidx, out, x0t, ybf,
                                         img, w0, b0, stat);
  k_conv1n<<<dim3(B, 32), 256, 0, stream>>>(x0t, wr1, sidx, x1, stat);
  k_proj_qkv<<<dim3(B, 40), 256, 0, stream>>>(x1, wq, bq, wk, bk, wv, bv, sidx, stat,
                                              q, k, vpk);
  k_attn<<<B * 64, 256, 0, stream>>>(q, k, vpk, x1, gamma, sidx, stat, ybf);
  k_conv2n<<<dim3(B, 32), 256, 0, stream>>>(ybf, wr2, sidx, x2);
  k_head_part<<<dim3(B, 8), 256, 0, stream>>>(x2, wh, sidx, out);
}

// Round 12
// 197.589 us; speedup vs baseline: 1.3774x; 1.0003x over previous
//
#include <hip/hip_runtime.h>

#define LRELU(x) ((x) > 0.0f ? (x) : 0.2f * (x))
#define SB __builtin_amdgcn_sched_barrier(0)

typedef short bf16x8 __attribute__((ext_vector_type(8)));
typedef short bf16x4 __attribute__((ext_vector_type(4)));
typedef float f32x4 __attribute__((ext_vector_type(4)));

__device__ __forceinline__ short f2bf(float f) {
  union { float f; unsigned u; } x{f};
  return (short)((x.u + 0x7FFF + ((x.u >> 16) & 1)) >> 16);
}

// ---------------------------------------------------------------------------
// fused prologue: weight repack (float4-vectorized coalesced reads) +
// head-bias out init + border zeroing + x1-stat zeroing + conv0 (>= 2853).
__global__ __launch_bounds__(256) void k_repack_all(
    const float* __restrict__ w1, unsigned short* __restrict__ wr1,
    const float* __restrict__ w2, unsigned short* __restrict__ wr2,
    const float* __restrict__ bh, const int* __restrict__ sidx,
    float* __restrict__ out, unsigned short* __restrict__ x0t,
    unsigned short* __restrict__ ybf, const float* __restrict__ img,
    const float* __restrict__ w0, const float* __restrict__ b0,
    float* __restrict__ stat) {
  __shared__ float Ish[4 * 34];
  if (blockIdx.x >= 2853) {
    // ---- conv0 segment: img (B,1,128,128) -> x0t padded 66x66 NHWC bf16
    const int t = threadIdx.x;
    const int q = blockIdx.x - 2853;
    const int b = q >> 8, py = q & 255;
    const int oh = py >> 2, owb = (py & 3) << 4;
    const int s = sidx[b];
    const float* ip = img + (size_t)b * 16384;
    if (t < 136) {
      int r = t / 34, c = t % 34;
      int ih = 2 * oh - 1 + r, iw = 2 * owb - 1 + c;
      Ish[t] = ((unsigned)ih < 128u && (unsigned)iw < 128u) ? ip[ih * 128 + iw] : 0.f;
    }
    const int co = t & 63, ps = t >> 6;
    float wreg[16];
    const float* wp = w0 + (s * 64 + co) * 16;
#pragma unroll
    for (int i = 0; i < 16; i++) wreg[i] = wp[i];
    float bb = b0[s * 64 + co];
    __syncthreads();
    unsigned short* op = x0t + ((size_t)b * 4356 + (oh + 1) * 66 + (owb + 1)) * 64 + co;
#pragma unroll
    for (int j = 0; j < 4; j++) {
      int pl = ps * 4 + j;
      float acc = bb;
#pragma unroll
      for (int kh = 0; kh < 4; kh++)
#pragma unroll
        for (int kw = 0; kw < 4; kw++)
          acc += wreg[kh * 4 + kw] * Ish[kh * 34 + pl * 2 + kw];
      acc = LRELU(acc);
      op[pl * 64] = (unsigned short)f2bf(acc);
    }
    return;
  }
  int idx = blockIdx.x * 256 + threadIdx.x;
  if (idx < 131072) {
    float4 v = *(const float4*)(w1 + (size_t)idx * 4);
    int base = idx * 4;
    int tap0 = base & 15;
    int rest = base >> 4;
    int ci = rest & 63, sco = rest >> 6;
    unsigned short* d = wr1 + (size_t)sco * 1024 + ci;
    d[(tap0 + 0) * 64] = (unsigned short)f2bf(v.x);
    d[(tap0 + 1) * 64] = (unsigned short)f2bf(v.y);
    d[(tap0 + 2) * 64] = (unsigned short)f2bf(v.z);
    d[(tap0 + 3) * 64] = (unsigned short)f2bf(v.w);
    return;
  } else if (idx < 655360) {
    int i = idx - 131072;
    float4 v = *(const float4*)(w2 + (size_t)i * 4);
    int base = i * 4;
    int tap0 = base & 15;
    int rest = base >> 4;
    int ci = rest & 127, sco = rest >> 7;
    unsigned short* d = wr2 + (size_t)sco * 2048 + ci;
    d[(tap0 + 0) * 128] = (unsigned short)f2bf(v.x);
    d[(tap0 + 1) * 128] = (unsigned short)f2bf(v.y);
    d[(tap0 + 2) * 128] = (unsigned short)f2bf(v.z);
    d[(tap0 + 3) * 128] = (unsigned short)f2bf(v.w);
    return;
  } else if (idx < 658960) {
    int i = idx - 655360;
    if (i < 3600) out[i] = bh[sidx[i / 225]];
    return;
  } else if (idx < 692240) {
    int i = idx - 658960;
    int b = i / 2080, r = i % 2080;
    int pix = r >> 3, sub = r & 7;
    int row, col;
    if (pix < 66) { row = 0; col = pix; }
    else if (pix < 132) { row = 65; col = pix - 66; }
    else { int qq = pix - 132; row = 1 + (qq >> 1); col = (qq & 1) * 65; }
    bf16x8 z = {0, 0, 0, 0, 0, 0, 0, 0};
    *(bf16x8*)(x0t + ((size_t)b * 4356 + row * 66 + col) * 64 + sub * 8) = z;
    return;
  } else if (idx < 726032) {
    int i = idx - 692240;
    if (i >= 33792) return;
    int b = i / 2112, r = i % 2112;
    int pix = r >> 4, sub = r & 15;
    int row, col;
    if (pix < 34) { row = 0; col = pix; }
    else if (pix < 68) { row = 33; col = pix - 34; }
    else { int qq = pix - 68; row = 1 + (qq >> 1); col = (qq & 1) * 33; }
    bf16x8 z = {0, 0, 0, 0, 0, 0, 0, 0};
    *(bf16x8*)(ybf + ((size_t)b * 1156 + row * 34 + col) * 128 + sub * 8) = z;
    return;
  } else {
    int i = idx - 726032;
    if (i < 4096) stat[i] = 0.f;
    return;
  }
}

// ---------------------------------------------------------------------------
// conv1: LDS-staged MFMA GEMM + stat accumulation. 1-D grid 512, XCD-swizzled:
// bid = (b&7) + 8*((b>>3)*32 + y)  ->  all blocks of batch b on XCD b%8.
__global__ __launch_bounds__(256, 2) void k_conv1n(
    const unsigned short* __restrict__ x0t, const unsigned short* __restrict__ wr,
    const int* __restrict__ sidx, float* __restrict__ x1,
    float* __restrict__ stat) {
  __shared__ __align__(16) unsigned short Xs[26624];
  const int t = threadIdx.x;
  const int c = blockIdx.x & 7, rr = blockIdx.x >> 3;
  const int b = c + 8 * (rr >> 5);
  const int y = rr & 31;
  const int ne = y & 15;
  const int cog = y >> 4;
  const int s = sidx[b];
  const int lane = t & 63, wv = t >> 6;
  const int quad = lane >> 4, l16 = lane & 15;

  const unsigned short* gb = x0t + ((size_t)b * 4356 + 4 * ne * 66) * 64;
  {
    float4 v[13];
#pragma unroll
    for (int i = 0; i < 13; i++) v[i] = *(const float4*)(gb + (i * 256 + t) * 8);
#pragma unroll
    for (int i = 0; i < 13; i++) {
      int ba = (i * 256 + t) * 16;
      int sw = ba ^ (((ba >> 9) & 7) << 4);
      *(float4*)((char*)Xs + sw) = v[i];
    }
  }
  __syncthreads();

  const int co0w = cog * 64 + wv * 16;
  const unsigned short* ap = wr + ((size_t)(s * 128 + co0w + l16)) * 1024 + quad * 8;
  f32x4 acc[4];
#pragma unroll
  for (int nt = 0; nt < 4; nt++) acc[nt] = (f32x4){0.f, 0.f, 0.f, 0.f};

#pragma unroll
  for (int kc = 0; kc < 32; kc++) {
    const int tap = kc >> 1;
    const int cio = (kc & 1) * 32 + quad * 8;
    const int kh = tap >> 2, kw = tap & 3;
    bf16x8 af = *(const bf16x8*)(ap + kc * 32);
#pragma unroll
    for (int nt = 0; nt < 4; nt++) {
      int lr = 2 * (nt >> 1) + kh;
      int col = 2 * ((nt & 1) * 16 + l16) + kw;
      int ba = ((lr * 66 + col) * 64 + cio) * 2;
      int sw = ba ^ (((ba >> 9) & 7) << 4);
      bf16x8 bv = *(const bf16x8*)((const char*)Xs + sw);
      acc[nt] = __builtin_amdgcn_mfma_f32_16x16x32_bf16(af, bv, acc[nt], 0, 0, 0);
    }
  }

#pragma unroll
  for (int r = 0; r < 4; r++) {
    float sv = acc[0][r] + acc[1][r] + acc[2][r] + acc[3][r];
    float sq = acc[0][r] * acc[0][r] + acc[1][r] * acc[1][r] +
               acc[2][r] * acc[2][r] + acc[3][r] * acc[3][r];
#pragma unroll
    for (int o = 1; o < 16; o <<= 1) {
      sv += __shfl_xor(sv, o, 64);
      sq += __shfl_xor(sq, o, 64);
    }
    if (l16 == 0) {
      int co = co0w + quad * 4 + r;
      atomicAdd(&stat[(b * 128 + co) * 2 + 0], sv);
      atomicAdd(&stat[(b * 128 + co) * 2 + 1], sq);
    }
  }

#pragma unroll
  for (int nt = 0; nt < 4; nt++) {
    int p = ne * 64 + (nt >> 1) * 32 + (nt & 1) * 16 + l16;
#pragma unroll
    for (int r = 0; r < 4; r++)
      x1[((size_t)b * 128 + co0w + quad * 4 + r) * 1024 + p] = acc[nt][r];
  }
}

// ---------------------------------------------------------------------------
// fused q/k/v 1x1 projections over RAW x1 (lazy norm). 1-D grid 640,
// XCD-swizzled: bid = (b&7) + 8*((b>>3)*40 + y).
__global__ __launch_bounds__(256) void k_proj_qkv(
    const float* __restrict__ xin, const float* __restrict__ wq,
    const float* __restrict__ bq, const float* __restrict__ wk,
    const float* __restrict__ bk, const float* __restrict__ wv,
    const float* __restrict__ bv, const int* __restrict__ sidx,
    const float* __restrict__ stat,
    float* __restrict__ q, float* __restrict__ kout, unsigned short* __restrict__ vpk) {
  __shared__ float xsh[32 * 256];
  __shared__ float wsh[16 * 32];
  __shared__ float msh[128], ish[128];
  const int t = threadIdx.x;
  const int c = blockIdx.x & 7, rr = blockIdx.x >> 3;
  const int half = (rr >= 40) ? 1 : 0;
  const int b = c + 8 * half;
  const int y = rr - half * 40;
  const int s = sidx[b];
  const int cg = t >> 6, ng = t & 63;
  const float* w;
  const float* bias;
  int co0, nn0, CO;
  if (y < 8) {
    w = (y < 4) ? wq : wk;
    bias = (y < 4) ? bq : bk;
    co0 = 0;
    nn0 = (y & 3) * 256;
    CO = 16;
  } else {
    w = wv;
    bias = bv;
    co0 = ((y - 8) >> 2) * 16;
    nn0 = ((y - 8) & 3) * 256;
    CO = 128;
  }
  if (t < 128) {
    float sv = stat[(b * 128 + t) * 2 + 0];
    float sq = stat[(b * 128 + t) * 2 + 1];
    float m = sv * (1.0f / 1024.0f);
    float var = sq * (1.0f / 1024.0f) - m * m;
    msh[t] = m;
    ish[t] = rsqrtf(var + 1e-5f);
  }
  const float* xb = xin + (size_t)b * 128 * 1024;
  float4 acc4[4];
#pragma unroll
  for (int cix = 0; cix < 4; cix++) {
    float bb = bias[s * CO + co0 + cg * 4 + cix];
    acc4[cix] = make_float4(bb, bb, bb, bb);
  }
  __syncthreads();
  for (int cc = 0; cc < 4; cc++) {
#pragma unroll
    for (int k = 0; k < 8; k++) {
      int id = t + (k << 8);
      int ci = id >> 6, nf = id & 63;
      float4 v = ((const float4*)(xb + (cc * 32 + ci) * 1024 + nn0))[nf];
      float m = msh[cc * 32 + ci], iv = ish[cc * 32 + ci];
      v.x = (v.x - m) * iv; v.x = LRELU(v.x);
      v.y = (v.y - m) * iv; v.y = LRELU(v.y);
      v.z = (v.z - m) * iv; v.z = LRELU(v.z);
      v.w = (v.w - m) * iv; v.w = LRELU(v.w);
      ((float4*)xsh)[id] = v;
    }
    if (t < 128)
      ((float4*)wsh)[t] =
          ((const float4*)(w + ((size_t)(s * CO + co0 + (t >> 3))) * 128 + cc * 32))[t & 7];
    __syncthreads();
#pragma unroll
    for (int ci4 = 0; ci4 < 8; ci4++) {
      float4 wvv[4], xv[4];
#pragma unroll
      for (int cix = 0; cix < 4; cix++) wvv[cix] = ((const float4*)wsh)[(cg * 4 + cix) * 8 + ci4];
#pragma unroll
      for (int i = 0; i < 4; i++) xv[i] = ((const float4*)xsh)[(ci4 * 4 + i) * 64 + ng];
#pragma unroll
      for (int cix = 0; cix < 4; cix++)
#pragma unroll
        for (int i = 0; i < 4; i++) {
          float wvc = i == 0 ? wvv[cix].x : i == 1 ? wvv[cix].y : i == 2 ? wvv[cix].z : wvv[cix].w;
          acc4[cix].x += wvc * xv[i].x;
          acc4[cix].y += wvc * xv[i].y;
          acc4[cix].z += wvc * xv[i].z;
          acc4[cix].w += wvc * xv[i].w;
        }
    }
    __syncthreads();
  }
  if (y < 8) {
    float* outp = (y < 4) ? q : kout;
#pragma unroll
    for (int cix = 0; cix < 4; cix++)
      ((float4*)(outp + ((size_t)b * 16 + cg * 4 + cix) * 1024 + nn0))[ng] = acc4[cix];
  } else {
    int n = nn0 + ng * 4;
#pragma unroll
    for (int cix = 0; cix < 4; cix++) {
      int co = co0 + cg * 4 + cix;
      bf16x4 u;
      u[0] = f2bf(acc4[cix].x);
      u[1] = f2bf(acc4[cix].y);
      u[2] = f2bf(acc4[cix].z);
      u[3] = f2bf(acc4[cix].w);
      *(bf16x4*)(vpk + (((size_t)b * 32 + (n >> 5)) * 128 + co) * 32 + (n & 31)) = u;
    }
  }
}

// ---------------------------------------------------------------------------
// fused self-attention. 1-D grid 1024, XCD-swizzled:
// bid = (b&7) + 8*((b>>3)*64 + n0idx) -> batch's K/V/q stay in one XCD's L2.
__global__ __launch_bounds__(256, 2) void k_attn(
    const float* __restrict__ q, const float* __restrict__ k,
    const unsigned short* __restrict__ vpk, const float* __restrict__ x1,
    const float* __restrict__ gamma, const int* __restrict__ sidx,
    const float* __restrict__ stat, unsigned short* __restrict__ ybf) {
  __shared__ __align__(16) short Psh[16 * 1032];
  __shared__ float qsh[256];
  __shared__ float redm[64], reds[64];
  const int t = threadIdx.x;
  const int c = blockIdx.x & 7, rr = blockIdx.x >> 3;
  const int b = c + 8 * (rr >> 6);
  const int n0 = (rr & 63) << 4;
  const int lane = t & 63, wv = t >> 6;
  const int quad = lane >> 4, l16 = lane & 15;
  const float* qb = q + (size_t)b * 16 * 1024;
  const float* kb = k + (size_t)b * 16 * 1024;
  const float* xb = x1 + (size_t)b * 128 * 1024;

  qsh[t] = qb[((t >> 4) << 10) + n0 + (t & 15)];
  __syncthreads();

  float acc[4][16];
#pragma unroll
  for (int j = 0; j < 4; j++)
#pragma unroll
    for (int nl = 0; nl < 16; nl++) acc[j][nl] = 0.0f;

  float4 KA[4], KB[4];
#define LDK(BUF, G)                                                       \
  _Pragma("unroll") for (int c4 = 0; c4 < 4; c4++)                        \
      BUF[c4] = *(const float4*)(kb + ((((G) * 4 + c4)) << 10) + 4 * t);  \
  SB;
#define MMK(BUF, G)                                                                         \
  _Pragma("unroll") for (int c4 = 0; c4 < 4; c4++) {                                        \
    const float* qr = qsh + ((G) * 4 + c4) * 16;                                            \
    _Pragma("unroll") for (int j = 0; j < 4; j++) {                                         \
      float kk = j == 0 ? BUF[c4].x : j == 1 ? BUF[c4].y : j == 2 ? BUF[c4].z : BUF[c4].w;  \
      _Pragma("unroll") for (int nl = 0; nl < 16; nl++) acc[j][nl] += kk * qr[nl];          \
    }                                                                                       \
  }                                                                                         \
  SB;

  LDK(KA, 0)
  LDK(KB, 1)
  MMK(KA, 0) LDK(KA, 2)
  MMK(KB, 1) LDK(KB, 3)
  MMK(KA, 2)
  MMK(KB, 3)
#undef LDK
#undef MMK

  float lmax[16];
#pragma unroll
  for (int nl = 0; nl < 16; nl++)
    lmax[nl] = fmaxf(fmaxf(acc[0][nl], acc[1][nl]), fmaxf(acc[2][nl], acc[3][nl]));
#pragma unroll
  for (int o = 32; o > 0; o >>= 1)
#pragma unroll
    for (int nl = 0; nl < 16; nl++) lmax[nl] = fmaxf(lmax[nl], __shfl_xor(lmax[nl], o, 64));
  if (lane == 0)
#pragma unroll
    for (int nl = 0; nl < 16; nl++) redm[wv * 16 + nl] = lmax[nl];
  __syncthreads();
#pragma unroll
  for (int nl = 0; nl < 16; nl++)
    lmax[nl] = fmaxf(fmaxf(redm[nl], redm[16 + nl]), fmaxf(redm[32 + nl], redm[48 + nl]));
  float lsum[16];
#pragma unroll
  for (int nl = 0; nl < 16; nl++) lsum[nl] = 0.0f;
#pragma unroll
  for (int j = 0; j < 4; j++)
#pragma unroll
    for (int nl = 0; nl < 16; nl++) {
      float e = __expf(acc[j][nl] - lmax[nl]);
      acc[j][nl] = e;
      lsum[nl] += e;
    }
#pragma unroll
  for (int o = 32; o > 0; o >>= 1)
#pragma unroll
    for (int nl = 0; nl < 16; nl++) lsum[nl] += __shfl_xor(lsum[nl], o, 64);
  if (lane == 0)
#pragma unroll
    for (int nl = 0; nl < 16; nl++) reds[wv * 16 + nl] = lsum[nl];
#pragma unroll
  for (int nl = 0; nl < 16; nl++) {
    bf16x4 pv;
    pv[0] = f2bf(acc[0][nl]);
    pv[1] = f2bf(acc[1][nl]);
    pv[2] = f2bf(acc[2][nl]);
    pv[3] = f2bf(acc[3][nl]);
    *(bf16x4*)&Psh[nl * 1032 + 4 * t] = pv;
  }
  __syncthreads();

  const unsigned short* vp =
      vpk + ((size_t)b * 32 * 128 + (size_t)(wv * 32 + l16)) * 32 + quad * 8;
  const short* prow = Psh + l16 * 1032 + quad * 8;
  f32x4 dacc[2];
  dacc[0] = (f32x4){0.f, 0.f, 0.f, 0.f};
  dacc[1] = (f32x4){0.f, 0.f, 0.f, 0.f};

  bf16x8 VA0[4], VA1[4], PAr[4];
  bf16x8 VB0[4], VB1[4], PBr[4];
#define LDV(V0, V1, PR, G)                                \
  _Pragma("unroll") for (int m4 = 0; m4 < 4; m4++) {      \
    int mt = (G) * 4 + m4;                                \
    V0[m4] = *(const bf16x8*)(vp + mt * 4096);            \
    V1[m4] = *(const bf16x8*)(vp + 512 + mt * 4096);      \
    PR[m4] = *(const bf16x8*)(prow + mt * 32);            \
  }                                                       \
  SB;
#define MMV(V0, V1, PR)                                                                      \
  _Pragma("unroll") for (int m4 = 0; m4 < 4; m4++) {                                         \
    dacc[0] = __builtin_amdgcn_mfma_f32_16x16x32_bf16(V0[m4], PR[m4], dacc[0], 0, 0, 0);     \
    dacc[1] = __builtin_amdgcn_mfma_f32_16x16x32_bf16(V1[m4], PR[m4], dacc[1], 0, 0, 0);     \
  }                                                                                          \
  SB;

  LDV(VA0, VA1, PAr, 0)
  LDV(VB0, VB1, PBr, 1)
  MMV(VA0, VA1, PAr) LDV(VA0, VA1, PAr, 2)
  MMV(VB0, VB1, PBr) LDV(VB0, VB1, PBr, 3)
  MMV(VA0, VA1, PAr) LDV(VA0, VA1, PAr, 4)
  MMV(VB0, VB1, PBr) LDV(VB0, VB1, PBr, 5)
  MMV(VA0, VA1, PAr) LDV(VA0, VA1, PAr, 6)
  MMV(VB0, VB1, PBr) LDV(VB0, VB1, PBr, 7)
  MMV(VA0, VA1, PAr)
  MMV(VB0, VB1, PBr)
#undef LDV
#undef MMV
  __syncthreads();

  float* Osh = (float*)Psh;
  short* Osh2 = Psh + 4352;
#pragma unroll
  for (int i = 0; i < 2; i++) {
    int cob = wv * 32 + i * 16 + quad * 4;
#pragma unroll
    for (int r = 0; r < 4; r++) Osh[(cob + r) * 17 + l16] = dacc[i][r];
  }
  __syncthreads();
  float g = gamma[sidx[b]];
  {
    int co = t >> 1, j0 = (t & 1) * 8;
    float sv = stat[(b * 128 + co) * 2 + 0];
    float sq = stat[(b * 128 + co) * 2 + 1];
    float mm = sv * (1.0f / 1024.0f);
    float iv = rsqrtf(sq * (1.0f / 1024.0f) - mm * mm + 1e-5f);
    const float* xr = xb + (co << 10) + n0 + j0;
    float4 xv0 = *(const float4*)xr;
    float4 xv1 = *(const float4*)(xr + 4);
    float xs[8] = {xv0.x, xv0.y, xv0.z, xv0.w, xv1.x, xv1.y, xv1.z, xv1.w};
#pragma unroll
    for (int j = 0; j < 8; j++) {
      float nv = (xs[j] - mm) * iv;
      xs[j] = LRELU(nv);
    }
#pragma unroll
    for (int j = 0; j < 8; j++) {
      int nl = j0 + j;
      float rs = 1.0f / (reds[nl] + reds[16 + nl] + reds[32 + nl] + reds[48 + nl]);
      Osh2[nl * 136 + co] = f2bf(g * Osh[co * 17 + nl] * rs + xs[j]);
    }
  }
  __syncthreads();
  {
    int nl = t >> 4, cg = t & 15;
    bf16x8 u = *(const bf16x8*)&Osh2[nl * 136 + cg * 8];
    int p = n0 + nl;
    int ih = p >> 5, iw = p & 31;
    *(bf16x8*)(ybf + ((size_t)b * 1156 + (ih + 1) * 34 + (iw + 1)) * 128 + cg * 8) = u;
  }
}

// ---------------------------------------------------------------------------
// conv2: LDS-staged MFMA GEMM. 1-D grid 512, XCD-swizzled like conv1.
__global__ __launch_bounds__(256, 2) void k_conv2n(
    const unsigned short* __restrict__ ybf, const unsigned short* __restrict__ wr,
    const int* __restrict__ sidx, float* __restrict__ x2) {
  __shared__ __align__(16) unsigned short Xs[26624];
  const int t = threadIdx.x;
  const int c = blockIdx.x & 7, rr = blockIdx.x >> 3;
  const int b = c + 8 * (rr >> 5);
  const int y = rr & 31;
  const int ne = y & 7;
  const int cog = y >> 3;
  const int s = sidx[b];
  const int lane = t & 63, wv = t >> 6;
  const int quad = lane >> 4, l16 = lane & 15;

  const unsigned short* gb = ybf + ((size_t)b * 1156 + 4 * ne * 34) * 128;
  {
    float4 v[13];
#pragma unroll
    for (int i = 0; i < 13; i++) v[i] = *(const float4*)(gb + (i * 256 + t) * 8);
#pragma unroll
    for (int i = 0; i < 13; i++) {
      int ba = (i * 256 + t) * 16;
      int sw = ba ^ (((ba >> 9) & 7) << 4);
      *(float4*)((char*)Xs + sw) = v[i];
    }
  }
  __syncthreads();

  const int co0w = cog * 64 + wv * 16;
  const unsigned short* ap = wr + ((size_t)(s * 256 + co0w + l16)) * 2048 + quad * 8;
  f32x4 acc[2];
  acc[0] = (f32x4){0.f, 0.f, 0.f, 0.f};
  acc[1] = (f32x4){0.f, 0.f, 0.f, 0.f};

#pragma unroll
  for (int kc = 0; kc < 64; kc++) {
    const int tap = kc >> 2;
    const int cio = (kc & 3) * 32 + quad * 8;
    const int kh = tap >> 2, kw = tap & 3;
    bf16x8 af = *(const bf16x8*)(ap + kc * 32);
#pragma unroll
    for (int nt = 0; nt < 2; nt++) {
      int lr = 2 * nt + kh;
      int col = 2 * l16 + kw;
      int ba = ((lr * 34 + col) * 128 + cio) * 2;
      int sw = ba ^ (((ba >> 9) & 7) << 4);
      bf16x8 bv = *(const bf16x8*)((const char*)Xs + sw);
      acc[nt] = __builtin_amdgcn_mfma_f32_16x16x32_bf16(af, bv, acc[nt], 0, 0, 0);
    }
  }

#pragma unroll
  for (int nt = 0; nt < 2; nt++) {
    int p = ne * 32 + nt * 16 + l16;
#pragma unroll
    for (int r = 0; r < 4; r++)
      x2[((size_t)b * 256 + co0w + quad * 4 + r) * 256 + p] = acc[nt][r];
  }
}

// ---------------------------------------------------------------------------
// head: x2 instance-norm (+leaky) FUSED into the head conv (x2 arrives RAW).
__global__ __launch_bounds__(256) void k_head_part(
    const float* __restrict__ x2, const float* __restrict__ wh,
    const int* __restrict__ sidx, float* __restrict__ out) {
  __shared__ float Xs[32 * 256];
  __shared__ float Wsh[512];
  __shared__ float sm[32], si[32];
  const int t = threadIdx.x;
  const int b = blockIdx.x, cc = blockIdx.y;
  const int s = sidx[b];
  const float* xp = x2 + ((size_t)b * 256 + cc * 32) * 256;
#pragma unroll
  for (int i = 0; i < 32; i++) Xs[i * 256 + t] = xp[i * 256 + t];
#pragma unroll
  for (int i = 0; i < 2; i++) {
    int idx = i * 256 + t;
    Wsh[idx] = wh[s * 4096 + cc * 512 + idx];
  }
  __syncthreads();
  {
    int r = t >> 3, c0 = (t & 7) * 32;
    float sv = 0.f, sq = 0.f;
#pragma unroll
    for (int j = 0; j < 32; j++) {
      float v = Xs[r * 256 + c0 + j];
      sv += v;
      sq += v * v;
    }
#pragma unroll
    for (int o = 1; o < 8; o <<= 1) {
      sv += __shfl_xor(sv, o, 64);
      sq += __shfl_xor(sq, o, 64);
    }
    if ((t & 7) == 0) {
      float m = sv * (1.0f / 256.0f);
      float var = sq * (1.0f / 256.0f) - m * m;
      sm[r] = m;
      si[r] = rsqrtf(var + 1e-5f);
    }
  }
  __syncthreads();
#pragma unroll
  for (int i = 0; i < 32; i++) {
    float v = (Xs[i * 256 + t] - sm[i]) * si[i];
    Xs[i * 256 + t] = LRELU(v);
  }
  __syncthreads();
  if (t < 225) {
    int oh = t / 15, ow = t % 15;
    float acc = 0.0f;
    for (int ci = 0; ci < 32; ci++) {
      const float* xr = Xs + ci * 256;
      const float* wr = Wsh + ci * 16;
#pragma unroll
      for (int kh = 0; kh < 4; kh++) {
        int ih = oh - 1 + kh;
        if ((unsigned)ih >= 16u) continue;
#pragma unroll
        for (int kw = 0; kw < 4; kw++) {
          int iw = ow - 1 + kw;
          if ((unsigned)iw >= 16u) continue;
          acc += wr[kh * 4 + kw] * xr[(ih << 4) + iw];
        }
      }
    }
    atomicAdd(out + b * 225 + t, acc);
  }
}

// ---------------------------------------------------------------------------
extern "C" void kernel_launch(void* const* d_in, const int* in_sizes, int n_in,
                              void* d_out, int out_size, void* d_ws, size_t ws_size,
                              hipStream_t stream) {
  const float* img = (const float*)d_in[0];
  const int* sidx = (const int*)d_in[1];
  const float* w0 = (const float*)d_in[2];
  const float* b0 = (const float*)d_in[3];
  const float* w1 = (const float*)d_in[4];
  const float* w2 = (const float*)d_in[6];
  const float* wq = (const float*)d_in[8];
  const float* bq = (const float*)d_in[9];
  const float* wk = (const float*)d_in[10];
  const float* bk = (const float*)d_in[11];
  const float* wv = (const float*)d_in[12];
  const float* bv = (const float*)d_in[13];
  const float* gamma = (const float*)d_in[14];
  const float* wh = (const float*)d_in[15];
  const float* bh = (const float*)d_in[16];
  float* out = (float*)d_out;

  float* ws = (float*)d_ws;
  unsigned short* x0t = (unsigned short*)(ws);            // padded 66x66: 16*4356*64 shorts
  float* x1 = ws + 2359296;                               // [2.25M,4.25M)
  float* q = ws + 4456448;                                // [4.25M,4.5M)
  float* k = ws + 4718592;                                // [4.5M,4.75M)
  unsigned short* vpk = (unsigned short*)(ws + 4980736);  // [4.75M,5.75M)
  unsigned short* ybf = (unsigned short*)(ws + 6029312);  // padded 34x34: 16*1156*128 shorts
  float* x2 = ws + 7340032;                               // [7M,8M)
  float* stat = ws + 8650752;                             // [8.25M,+4096) x1 norm stats
  unsigned short* wr1 = (unsigned short*)(ws + 8912896);  // [8.5M,8.75M)
  unsigned short* wr2 = (unsigned short*)(ws + 9175040);  // [8.75M,9.75M)

  const int B = 16;
  (void)B;

  k_repack_all<<<6949, 256, 0, stream>>>(w1, wr1, w2, wr2, bh, sidx, out, x0t, ybf,
                                         img, w0, b0, stat);
  k_conv1n<<<512, 256, 0, stream>>>(x0t, wr1, sidx, x1, stat);
  k_proj_qkv<<<640, 256, 0, stream>>>(x1, wq, bq, wk, bk, wv, bv, sidx, stat, q, k, vpk);
  k_attn<<<1024, 256, 0, stream>>>(q, k, vpk, x1, gamma, sidx, stat, ybf);
  k_conv2n<<<512, 256, 0, stream>>>(ybf, wr2, sidx, x2);
  k_head_part<<<dim3(16, 8), 256, 0, stream>>>(x2, wh, sidx, out);
}